// Round 13
// baseline (708.229 us; speedup 1.0000x reference)
//
#include <hip/hip_runtime.h>
#include <hip/hip_bf16.h>
#include <stdint.h>

#define NND 40000
#define NE  640000
#define NG  128
#define DIM 128
#define HID 64
#define ADJ_BLOCKS 640
#define NOISY_BLOCKS 5000   // NND*32/256
#define NSCB ((NND + 255) / 256)   // 157 scan blocks
#define EMB_SPLIT 8
#define SROWS 313            // gemm row blocks (128 rows each) = stats rows
#define CVB 2500             // convert blocks

typedef short v8s __attribute__((ext_vector_type(8)));
typedef float v4f __attribute__((ext_vector_type(4)));

// ---------------- threefry2x32 (20 rounds), JAX-compatible ----------------
__host__ __device__ inline uint32_t rotl32(uint32_t v, uint32_t r) {
    return (v << r) | (v >> (32u - r));
}

__host__ __device__ inline void threefry2x32(uint32_t k0, uint32_t k1,
                                             uint32_t& x0, uint32_t& x1) {
    uint32_t k2 = k0 ^ k1 ^ 0x1BD11BDAu;
    x0 += k0; x1 += k1;
#define TFR(r) { x0 += x1; x1 = rotl32(x1, r); x1 ^= x0; }
    TFR(13u) TFR(15u) TFR(26u) TFR(6u)
    x0 += k1; x1 += k2 + 1u;
    TFR(17u) TFR(29u) TFR(16u) TFR(24u)
    x0 += k2; x1 += k0 + 2u;
    TFR(13u) TFR(15u) TFR(26u) TFR(6u)
    x0 += k0; x1 += k1 + 3u;
    TFR(17u) TFR(29u) TFR(16u) TFR(24u)
    x0 += k1; x1 += k2 + 4u;
    TFR(13u) TFR(15u) TFR(26u) TFR(6u)
    x0 += k2; x1 += k0 + 5u;
#undef TFR
}

__device__ inline float rbits_u01(uint32_t k0, uint32_t k1, uint32_t idx) {
    uint32_t x0 = 0u, x1 = idx;
    threefry2x32(k0, k1, x0, x1);
    uint32_t b = x0 ^ x1;
    return __uint_as_float((b >> 9) | 0x3f800000u) - 1.0f;
}

__device__ inline ushort bfbits(float a) {
    __hip_bfloat16 h = __float2bfloat16(a);
    return *(ushort*)&h;
}

__device__ inline uint32_t bfpack(float a, float b) {
    return (uint32_t)bfbits(a) | ((uint32_t)bfbits(b) << 16);
}

#define UNPACK8(v, f)                                                     \
    f[0] = __uint_as_float((v).x << 16); f[1] = __uint_as_float((v).x & 0xffff0000u); \
    f[2] = __uint_as_float((v).y << 16); f[3] = __uint_as_float((v).y & 0xffff0000u); \
    f[4] = __uint_as_float((v).z << 16); f[5] = __uint_as_float((v).z & 0xffff0000u); \
    f[6] = __uint_as_float((v).w << 16); f[7] = __uint_as_float((v).w & 0xffff0000u);

// ---------------- last-block helper (device-scope fence + counter) ----------------
__device__ __forceinline__ bool last_block(int* counter, int total) {
    __shared__ int amLast;
    __threadfence();
    if (threadIdx.x == 0) {
        int v = atomicAdd(counter, 1);
        amLast = (v == total - 1) ? 1 : 0;
    }
    __syncthreads();
    if (amLast) __threadfence();
    return amLast != 0;
}

// winner-side stats finalize: sscr[nblk][2M] -> cs (affine: scale/shift; else raw)
template <int M>
__device__ void stats_finalize(const float* __restrict__ sscr, int nblk,
                               const float* __restrict__ g, const float* __restrict__ b,
                               float* __restrict__ cs, int affine) {
    const int cols = 2 * M;
    for (int c = threadIdx.x; c < M; c += blockDim.x) {
        float s = 0.f, q = 0.f;
#pragma unroll 4
        for (int r = 0; r < nblk; r++) {
            s += sscr[(size_t)r * cols + c];
            q += sscr[(size_t)r * cols + M + c];
        }
        if (affine) {
            const float invN = 1.0f / (float)NND;
            float mu = s * invN;
            float var = fmaxf(q * invN - mu * mu, 0.f);
            float sc = g[c] * rsqrtf(var + 1e-5f);
            cs[c] = sc;
            cs[M + c] = b[c] - mu * sc;
        } else {
            cs[c] = s;
            cs[M + c] = q;
        }
    }
}

// ---------------- fused convert: x->bf16, gstart, zero deg + counters ----------
__global__ __launch_bounds__(256) void cvt_fused_kernel(const float* __restrict__ in,
                                                        ushort* __restrict__ outh,
                                                        const int* __restrict__ batch,
                                                        int* __restrict__ gstart,
                                                        int* __restrict__ deg,
                                                        int* __restrict__ cnt) {
    int blk = blockIdx.x, t = threadIdx.x;
    if (blk < CVB) {
        int i = blk * 256 + t;
        const float4* p = (const float4*)in + (size_t)i * 2;
        float4 a = p[0], b = p[1];
        uint4 o;
        o.x = bfpack(a.x, a.y); o.y = bfpack(a.z, a.w);
        o.z = bfpack(b.x, b.y); o.w = bfpack(b.z, b.w);
        *(uint4*)(outh + (size_t)i * 8) = o;
    } else if (blk < CVB + NSCB) {
        int i = (blk - CVB) * 256 + t;
        if (i < NND) {
            int b = batch[i];
            int prev = (i == 0) ? -1 : batch[i - 1];
            for (int g = prev + 1; g <= b; g++) gstart[g] = i;
            if (i == NND - 1)
                for (int g = b + 1; g <= NG; g++) gstart[g] = NND;
        }
    } else {
        int i = (blk - CVB - NSCB) * 256 + t;
        if (i < NND) deg[i] = 0;
        if (blk == CVB + NSCB && t < 160) cnt[t] = 0;
    }
}

// ---------------- CSR build ----------------
__global__ __launch_bounds__(256) void hist_kernel(const int* __restrict__ dst,
                                                   int* __restrict__ deg) {
    int e = blockIdx.x * 256 + threadIdx.x;
    if (e < NE) atomicAdd(&deg[dst[e]], 1);
}

// block sums + last-block computes exclusive block offsets (boff) and offv[NND]
__global__ __launch_bounds__(256) void scan_bsum_kernel(const int* __restrict__ deg,
                                                        int* __restrict__ bsum,
                                                        int* __restrict__ boff,
                                                        int* __restrict__ offv,
                                                        int* __restrict__ cnt) {
    int t = threadIdx.x;
    int i = blockIdx.x * 256 + t;
    int v = (i < NND) ? deg[i] : 0;
    __shared__ int sh[256];
    sh[t] = v;
    __syncthreads();
#pragma unroll
    for (int s = 128; s > 0; s >>= 1) {
        if (t < s) sh[t] += sh[t + s];
        __syncthreads();
    }
    if (t == 0) bsum[blockIdx.x] = sh[0];

    if (last_block(cnt, NSCB)) {
        int bv = (t < NSCB) ? bsum[t] : 0;
        __syncthreads();
        sh[t] = bv;
        __syncthreads();
        for (int d = 1; d < 256; d <<= 1) {
            int u = (t >= d) ? sh[t - d] : 0;
            __syncthreads();
            sh[t] += u;
            __syncthreads();
        }
        if (t < NSCB) boff[t] = sh[t] - bv;
        if (t == NSCB - 1) offv[NND] = sh[t];
    }
}

__global__ __launch_bounds__(256) void scan_final_kernel(const int* __restrict__ deg,
                                                         const int* __restrict__ boff,
                                                         int* __restrict__ offv,
                                                         int* __restrict__ cursor) {
    int t = threadIdx.x;
    int i = blockIdx.x * 256 + t;
    int v = (i < NND) ? deg[i] : 0;
    __shared__ int sh[256];
    sh[t] = v;
    __syncthreads();
    for (int d = 1; d < 256; d <<= 1) {
        int u = (t >= d) ? sh[t - d] : 0;
        __syncthreads();
        sh[t] += u;
        __syncthreads();
    }
    int off = boff[blockIdx.x] + sh[t] - v;
    if (i < NND) { offv[i] = off; cursor[i] = off; }
}

__global__ __launch_bounds__(256) void build_kernel(const int* __restrict__ src,
                                                    const int* __restrict__ dst,
                                                    int* __restrict__ cursor,
                                                    int* __restrict__ elist) {
    int e = blockIdx.x * 256 + threadIdx.x;
    if (e < NE) {
        int p = atomicAdd(&cursor[dst[e]], 1);
        elist[p] = src[e];
    }
}

// ---------------- gather: wave/node, 4 edge-slots x 16 col-slots; bf16 in/out.
// AFF=1: apply per-column affine+relu to each loaded element (BN fold).
template <int AFF>
__global__ __launch_bounds__(256) void gather_kernel(const ushort* __restrict__ feath,
                                                     const int* __restrict__ offv,
                                                     const int* __restrict__ elist,
                                                     ushort* __restrict__ aggh,
                                                     const float* __restrict__ cs) {
    int gt = blockIdx.x * 256 + threadIdx.x;
    int n = gt >> 6;
    int lane = threadIdx.x & 63;
    int e = lane >> 4, c = lane & 15;
    const uint4* F = (const uint4*)feath;
    int o0 = offv[n], o1 = offv[n + 1];

    float sc[8], sh[8];
    if (AFF) {
#pragma unroll
        for (int j = 0; j < 8; j++) {
            sc[j] = cs[c * 8 + j];
            sh[j] = cs[DIM + c * 8 + j];
        }
    }

    float acc[8];
    if (e == 0) {
        uint4 v = F[(size_t)n * 16 + c];
        UNPACK8(v, acc)
        if (AFF) {
#pragma unroll
            for (int j = 0; j < 8; j++) acc[j] = fmaxf(fmaf(acc[j], sc[j], sh[j]), 0.f);
        }
    } else {
#pragma unroll
        for (int j = 0; j < 8; j++) acc[j] = 0.f;
    }

    for (int i = o0 + e; i < o1; i += 4) {
        int s = elist[i];
        uint4 v = F[(size_t)s * 16 + c];
        float f[8];
        UNPACK8(v, f)
        if (AFF) {
#pragma unroll
            for (int j = 0; j < 8; j++) f[j] = fmaxf(fmaf(f[j], sc[j], sh[j]), 0.f);
        }
#pragma unroll
        for (int j = 0; j < 8; j++) acc[j] += f[j];
    }

#pragma unroll
    for (int j = 0; j < 8; j++) {
        acc[j] += __shfl_xor(acc[j], 16);
        acc[j] += __shfl_xor(acc[j], 32);
    }

    uint32_t wv;
    if (e == 0)      wv = bfpack(acc[0], acc[1]);
    else if (e == 1) wv = bfpack(acc[2], acc[3]);
    else if (e == 2) wv = bfpack(acc[4], acc[5]);
    else             wv = bfpack(acc[6], acc[7]);
    ((uint32_t*)aggh)[(size_t)n * 64 + c * 4 + e] = wv;
}

// ---------------- fused GIN double-GEMM + last-block BN finalize ----------------
__global__ __launch_bounds__(256) void gin2_kernel(const ushort* __restrict__ Ah,
                                                   const float* __restrict__ Wa,
                                                   const float* __restrict__ Wb,
                                                   ushort* __restrict__ outh,
                                                   float* __restrict__ sscr,
                                                   const float* __restrict__ gv,
                                                   const float* __restrict__ bv_,
                                                   float* __restrict__ cs,
                                                   int* __restrict__ cnt,
                                                   int nrows) {
    constexpr int K = 128, KP = 136;
    extern __shared__ ushort lds[];
    ushort* B1 = lds;                 // KP*128
    ushort* B2 = lds + 128 * KP;      // KP*128

    const int t = threadIdx.x;
    const int w = t >> 6, l = t & 63;
    const int lm = l & 15, lk = l >> 4;
    const int row0 = blockIdx.x * 128 + w * 32;

    uint4 areg[2][4];
#pragma unroll
    for (int rf = 0; rf < 2; rf++) {
        int r = row0 + rf * 16 + lm;
        const ushort* ap = Ah + (size_t)min(r, nrows - 1) * K + lk * 8;
#pragma unroll
        for (int kc = 0; kc < 4; kc++)
            areg[rf][kc] = *(const uint4*)(ap + kc * 32);
    }

    for (int idx = t; idx < K * K; idx += 256) {
        int k = idx >> 7, c = idx & 127;
        B1[c * KP + k] = bfbits(Wa[idx]);
        B2[c * KP + k] = bfbits(Wb[idx]);
    }
    __syncthreads();

    v4f acc[2][8];
#pragma unroll
    for (int i = 0; i < 2; i++)
#pragma unroll
        for (int j = 0; j < 8; j++) acc[i][j] = (v4f){0.f, 0.f, 0.f, 0.f};

#pragma unroll
    for (int kc = 0; kc < 4; kc++) {
        v8s a0 = *(const v8s*)&areg[0][kc];
        v8s a1 = *(const v8s*)&areg[1][kc];
#pragma unroll
        for (int nc = 0; nc < 8; nc++) {
            v8s bfr = *(const v8s*)(B1 + (nc * 16 + lm) * KP + kc * 32 + lk * 8);
            acc[0][nc] = __builtin_amdgcn_mfma_f32_16x16x32_bf16(a0, bfr, acc[0][nc], 0, 0, 0);
            acc[1][nc] = __builtin_amdgcn_mfma_f32_16x16x32_bf16(a1, bfr, acc[1][nc], 0, 0, 0);
        }
    }

    __syncthreads();
#pragma unroll
    for (int rf = 0; rf < 2; rf++)
#pragma unroll
        for (int nc = 0; nc < 8; nc++)
#pragma unroll
            for (int reg = 0; reg < 4; reg++) {
                int r = w * 32 + rf * 16 + lk * 4 + reg;
                int c = nc * 16 + lm;
                B1[r * KP + c] = bfbits(fmaxf(acc[rf][nc][reg], 0.f));
            }
    __syncthreads();

    v4f acc2[2][8];
#pragma unroll
    for (int i = 0; i < 2; i++)
#pragma unroll
        for (int j = 0; j < 8; j++) acc2[i][j] = (v4f){0.f, 0.f, 0.f, 0.f};

#pragma unroll
    for (int kc = 0; kc < 4; kc++) {
        v8s a0 = *(const v8s*)(B1 + (w * 32 + lm) * KP + kc * 32 + lk * 8);
        v8s a1 = *(const v8s*)(B1 + (w * 32 + 16 + lm) * KP + kc * 32 + lk * 8);
#pragma unroll
        for (int nc = 0; nc < 8; nc++) {
            v8s bfr = *(const v8s*)(B2 + (nc * 16 + lm) * KP + kc * 32 + lk * 8);
            acc2[0][nc] = __builtin_amdgcn_mfma_f32_16x16x32_bf16(a0, bfr, acc2[0][nc], 0, 0, 0);
            acc2[1][nc] = __builtin_amdgcn_mfma_f32_16x16x32_bf16(a1, bfr, acc2[1][nc], 0, 0, 0);
        }
    }

    float ps[8], pq[8];
#pragma unroll
    for (int nc = 0; nc < 8; nc++) { ps[nc] = 0.f; pq[nc] = 0.f; }

#pragma unroll
    for (int nc = 0; nc < 8; nc++) {
        int cg = nc * 16 + lm;
#pragma unroll
        for (int rf = 0; rf < 2; rf++)
#pragma unroll
            for (int reg = 0; reg < 4; reg++) {
                int rg = row0 + rf * 16 + lk * 4 + reg;
                if (rg < nrows) {
                    float v = fmaxf(acc2[rf][nc][reg], 0.f);
                    outh[(size_t)rg * K + cg] = bfbits(v);
                    ps[nc] += v; pq[nc] += v * v;
                }
            }
    }

    __syncthreads();
    float* scr = (float*)lds;
#pragma unroll
    for (int nc = 0; nc < 8; nc++) {
        ps[nc] += __shfl_xor(ps[nc], 16); ps[nc] += __shfl_xor(ps[nc], 32);
        pq[nc] += __shfl_xor(pq[nc], 16); pq[nc] += __shfl_xor(pq[nc], 32);
    }
    if (lk == 0) {
#pragma unroll
        for (int nc = 0; nc < 8; nc++) {
            scr[w * 128 + nc * 16 + lm]       = ps[nc];
            scr[512 + w * 128 + nc * 16 + lm] = pq[nc];
        }
    }
    __syncthreads();
    if (t < 128) {
        float s = scr[t] + scr[128 + t] + scr[256 + t] + scr[384 + t];
        float q = scr[512 + t] + scr[640 + t] + scr[768 + t] + scr[896 + t];
        sscr[(size_t)blockIdx.x * 256 + t]       = s;
        sscr[(size_t)blockIdx.x * 256 + 128 + t] = q;
    }

    if (last_block(cnt, SROWS))
        stats_finalize<128>(sscr, SROWS, gv, bv_, cs, 1);
}

// ---------------- MFMA GEMM (single) + optional last-block stats ----------------
template <int K, int M, int ACT, int STATS, int PRE, int OUTM>
__global__ __launch_bounds__(256) void mgemm_kernel(const ushort* __restrict__ Ah,
                                                    const float* __restrict__ W,
                                                    const float* __restrict__ bias,
                                                    float* __restrict__ outf,
                                                    ushort* __restrict__ outh,
                                                    float* __restrict__ sscr,
                                                    const float* __restrict__ pscale,
                                                    const float* __restrict__ pshift,
                                                    const float* __restrict__ gv,
                                                    const float* __restrict__ bv_,
                                                    float* __restrict__ cs,
                                                    int* __restrict__ cnt,
                                                    int affine,
                                                    int nrows) {
    constexpr int KP  = K + 8;
    constexpr int NKC = K / 32;
    __shared__ __align__(16) ushort sW[64 * KP];

    const int t = threadIdx.x;
    const int w = t >> 6, l = t & 63;
    const int lm = l & 15, lk = l >> 4;
    const int col0 = blockIdx.y * 64;
    const int row0 = blockIdx.x * 128 + w * 32;

    for (int idx = t; idx < K * 64; idx += 256) {
        int k = idx >> 6, c = idx & 63;
        sW[c * KP + k] = bfbits(W[(size_t)k * M + col0 + c]);
    }

    uint4 areg[2][NKC];
#pragma unroll
    for (int rf = 0; rf < 2; rf++) {
        int r = row0 + rf * 16 + lm;
        const ushort* ap = Ah + (size_t)min(r, nrows - 1) * K + lk * 8;
#pragma unroll
        for (int kc = 0; kc < NKC; kc++)
            areg[rf][kc] = *(const uint4*)(ap + kc * 32);
    }

    __syncthreads();

    v4f acc[2][4];
#pragma unroll
    for (int i = 0; i < 2; i++)
#pragma unroll
        for (int j = 0; j < 4; j++) acc[i][j] = (v4f){0.f, 0.f, 0.f, 0.f};

#pragma unroll
    for (int kc = 0; kc < NKC; kc++) {
        v8s bfr[4];
#pragma unroll
        for (int nc = 0; nc < 4; nc++)
            bfr[nc] = *(const v8s*)(sW + (nc * 16 + lm) * KP + kc * 32 + lk * 8);

        v8s afr[2];
#pragma unroll
        for (int rf = 0; rf < 2; rf++) {
            if (PRE > 0) {
                int k0 = kc * 32 + lk * 8;
                float f[8];
                uint4 v = areg[rf][kc];
                UNPACK8(v, f)
                float4 s0 = *(const float4*)(pscale + k0);
                float4 s1 = *(const float4*)(pscale + k0 + 4);
                float4 h0 = *(const float4*)(pshift + k0);
                float4 h1 = *(const float4*)(pshift + k0 + 4);
                f[0] = fmaf(f[0], s0.x, h0.x); f[1] = fmaf(f[1], s0.y, h0.y);
                f[2] = fmaf(f[2], s0.z, h0.z); f[3] = fmaf(f[3], s0.w, h0.w);
                f[4] = fmaf(f[4], s1.x, h1.x); f[5] = fmaf(f[5], s1.y, h1.y);
                f[6] = fmaf(f[6], s1.z, h1.z); f[7] = fmaf(f[7], s1.w, h1.w);
                if (PRE == 2) {
#pragma unroll
                    for (int e2 = 0; e2 < 8; e2++) f[e2] = fmaxf(f[e2], 0.f);
                }
                v8s a;
#pragma unroll
                for (int e2 = 0; e2 < 8; e2++) a[e2] = (short)bfbits(f[e2]);
                afr[rf] = a;
            } else {
                afr[rf] = *(const v8s*)&areg[rf][kc];
            }
        }

#pragma unroll
        for (int rf = 0; rf < 2; rf++)
#pragma unroll
            for (int nc = 0; nc < 4; nc++)
                acc[rf][nc] = __builtin_amdgcn_mfma_f32_16x16x32_bf16(
                    afr[rf], bfr[nc], acc[rf][nc], 0, 0, 0);
    }

    float ps[4], pq[4];
#pragma unroll
    for (int nc = 0; nc < 4; nc++) { ps[nc] = 0.f; pq[nc] = 0.f; }

#pragma unroll
    for (int nc = 0; nc < 4; nc++) {
        int cg = col0 + nc * 16 + lm;
        float bv = bias ? bias[cg] : 0.f;
#pragma unroll
        for (int rf = 0; rf < 2; rf++) {
#pragma unroll
            for (int reg = 0; reg < 4; reg++) {
                int rg = row0 + rf * 16 + lk * 4 + reg;
                if (rg < nrows) {
                    float v = acc[rf][nc][reg] + bv;
                    if (ACT == 1) v = fmaxf(v, 0.f);
                    if (ACT == 2) v = tanhf(v);
                    if (OUTM != 0) outf[(size_t)rg * M + cg] = v;
                    if (OUTM != 1) outh[(size_t)rg * M + cg] = bfbits(v);
                    ps[nc] += v; pq[nc] += v * v;
                }
            }
        }
    }

    if (STATS) {
        __syncthreads();
        float* scr = (float*)sW;
#pragma unroll
        for (int nc = 0; nc < 4; nc++) {
            ps[nc] += __shfl_xor(ps[nc], 16); ps[nc] += __shfl_xor(ps[nc], 32);
            pq[nc] += __shfl_xor(pq[nc], 16); pq[nc] += __shfl_xor(pq[nc], 32);
        }
        if (lk == 0) {
#pragma unroll
            for (int nc = 0; nc < 4; nc++) {
                scr[w * 64 + nc * 16 + lm]       = ps[nc];
                scr[256 + w * 64 + nc * 16 + lm] = pq[nc];
            }
        }
        __syncthreads();
        if (t < 64) {
            float s = scr[t] + scr[64 + t] + scr[128 + t] + scr[192 + t];
            float q = scr[256 + t] + scr[320 + t] + scr[384 + t] + scr[448 + t];
            sscr[(size_t)blockIdx.x * 2 * M + col0 + t]     = s;
            sscr[(size_t)blockIdx.x * 2 * M + M + col0 + t] = q;
        }

        if (last_block(cnt, SROWS * (M / 64)))
            stats_finalize<M>(sscr, SROWS, gv, bv_, cs, affine);
    }
}

// ---------------- fused assign + noisy + kl partials ----------------
__global__ __launch_bounds__(256) void noisy_kernel(const float* __restrict__ nfeat,
                                                    const ushort* __restrict__ a1h,
                                                    const float* __restrict__ Wfc2,
                                                    const float* __restrict__ bfc2,
                                                    const float* __restrict__ cs3,
                                                    float* __restrict__ noisy,
                                                    float* __restrict__ assn,
                                                    float* __restrict__ kpart,
                                                    uint32_t kg0, uint32_t kg1,
                                                    uint32_t kn0, uint32_t kn1) {
    __shared__ float wsh[DIM * 2];
    int t = threadIdx.x;
    wsh[t] = Wfc2[t];
    __syncthreads();

    int gt = blockIdx.x * 256 + t;
    int n = gt >> 5, c4 = t & 31, d = c4 * 4;

    // assignment dot product: lanes of this node's 32-group cover k = c4*4..+3
    float d0 = 0.f, d1 = 0.f;
    {
        uint2 av = *(const uint2*)(a1h + (size_t)n * DIM + d);
        float a0 = __uint_as_float(av.x << 16);
        float a1 = __uint_as_float(av.x & 0xffff0000u);
        float a2 = __uint_as_float(av.y << 16);
        float a3 = __uint_as_float(av.y & 0xffff0000u);
        d0 = a0 * wsh[2 * d] + a1 * wsh[2 * (d + 1)] + a2 * wsh[2 * (d + 2)] + a3 * wsh[2 * (d + 3)];
        d1 = a0 * wsh[2 * d + 1] + a1 * wsh[2 * (d + 1) + 1] + a2 * wsh[2 * (d + 2) + 1] + a3 * wsh[2 * (d + 3) + 1];
    }
#pragma unroll
    for (int s = 16; s > 0; s >>= 1) {
        d0 += __shfl_xor(d0, s);
        d1 += __shfl_xor(d1, s);
    }

    float la0 = 0.f, la1 = 0.f;
    if (c4 == 0) {
        float dd0 = d0 + bfc2[0], dd1 = d1 + bfc2[1];
        float m = fmaxf(dd0, dd1);
        float e0 = expf(dd0 - m), e1 = expf(dd1 - m);
        float inv = 1.f / (e0 + e1);
        float as0 = e0 * inv, as1 = e1 * inv;
        assn[2 * n] = as0; assn[2 * n + 1] = as1;

        float uf0 = rbits_u01(kg0, kg1, (uint32_t)(2 * n));
        float uf1 = rbits_u01(kg0, kg1, (uint32_t)(2 * n + 1));
        float u0 = fmaxf(1e-10f, uf0 + 1e-10f);
        float u1 = fmaxf(1e-10f, uf1 + 1e-10f);
        float gu0 = -logf(-logf(u0));
        float gu1 = -logf(-logf(u1));
        float y0 = as0 + gu0, y1 = as1 + gu1;
        float mm = fmaxf(y0, y1);
        float f0 = expf(y0 - mm), f1 = expf(y1 - mm);
        float iv = 1.f / (f0 + f1);
        la0 = f0 * iv; la1 = f1 * iv;
    }
    la0 = __shfl(la0, 0, 32);
    la1 = __shfl(la1, 0, 32);

    const float invN = 1.0f / (float)NND;
    float4 xv = *(const float4*)(nfeat + (size_t)n * DIM + d);
    float xa[4] = {xv.x, xv.y, xv.z, xv.w};
    float t1 = 0.f, t2 = 0.f, o[4];
#pragma unroll
    for (int j = 0; j < 4; j++) {
        float mu = cs3[d + j] * invN;
        float q = cs3[DIM + d + j];
        float var1 = fmaxf(q - (float)NND * mu * mu, 0.f) / (float)(NND - 1);
        float sd = sqrtf(var1);
        float r = rbits_u01(kn0, kn1, (uint32_t)(n * DIM + d + j));
        float nm = la0 * xa[j] + la1 * mu;
        float ns = la1 * sd;
        o[j] = fmaf(r, ns, nm);
        float inv = 1.0f / (sd + 1e-7f);
        float z1 = ns * inv;            t1 += z1 * z1;
        float z2 = (nm - mu) * inv;     t2 += z2 * z2;
    }
    *(float4*)(noisy + (size_t)n * DIM + d) = make_float4(o[0], o[1], o[2], o[3]);

    __shared__ float s1[256], s2[256];
    s1[t] = t1; s2[t] = t2;
    __syncthreads();
    for (int s = 128; s > 0; s >>= 1) {
        if (t < s) { s1[t] += s1[t + s]; s2[t] += s2[t + s]; }
        __syncthreads();
    }
    if (t == 0) { kpart[2 * blockIdx.x] = s1[0]; kpart[2 * blockIdx.x + 1] = s2[0]; }
}

// ---------------- fused graph pooling + head (per-graph last-block) ----------------
__global__ __launch_bounds__(128) void emb_head_kernel(const float* __restrict__ noisy,
                                                       const int* __restrict__ gstart,
                                                       float* __restrict__ gpart,
                                                       const float* __restrict__ protos,
                                                       const float* __restrict__ Wlast,
                                                       float* __restrict__ out_logits,
                                                       float* __restrict__ out_probs,
                                                       float* __restrict__ emb_out,
                                                       float* __restrict__ out_sim,
                                                       float* __restrict__ out_dist,
                                                       int* __restrict__ gcnt) {
    int g = blockIdx.x / EMB_SPLIT;
    int sidx = blockIdx.x % EMB_SPLIT;
    int c = threadIdx.x;
    int s = gstart[g], e = gstart[g + 1];
    int len = e - s;
    int chunk = (len + EMB_SPLIT - 1) / EMB_SPLIT;
    int r0 = s + sidx * chunk;
    int r1 = min(r0 + chunk, e);
    float acc = 0.f;
    for (int r = r0; r < r1; r++) acc += noisy[(size_t)r * DIM + c];
    gpart[((size_t)g * EMB_SPLIT + sidx) * DIM + c] = acc;

    if (!last_block(&gcnt[g], EMB_SPLIT)) return;

    // reduce 8 partials, write graph embedding
    float tot = 0.f;
#pragma unroll
    for (int si = 0; si < EMB_SPLIT; si++)
        tot += gpart[((size_t)g * EMB_SPLIT + si) * DIM + c];
    float cntf = (float)len;
    float ev = tot / fmaxf(cntf, 1.f);
    emb_out[(size_t)g * DIM + c] = ev;

    __shared__ float se[DIM];
    se[c] = ev;
    __syncthreads();

    if (c < 64) {
        int l = c;
        float ge0 = se[l], ge1 = se[l + 64];
        float gn = ge0 * ge0 + ge1 * ge1;
        float dj[10], pj[10];
#pragma unroll
        for (int j = 0; j < 10; j++) {
            float pa = protos[j * DIM + l], pb = protos[j * DIM + l + 64];
            dj[j] = ge0 * pa + ge1 * pb;
            pj[j] = pa * pa + pb * pb;
        }
        float wl0 = ge0 * Wlast[10 + l] + ge1 * Wlast[10 + l + 64];
        float wl1 = ge0 * Wlast[138 + 10 + l] + ge1 * Wlast[138 + 10 + l + 64];
#pragma unroll
        for (int sft = 32; sft > 0; sft >>= 1) {
            gn += __shfl_xor(gn, sft);
            wl0 += __shfl_xor(wl0, sft);
            wl1 += __shfl_xor(wl1, sft);
#pragma unroll
            for (int j = 0; j < 10; j++) {
                dj[j] += __shfl_xor(dj[j], sft);
                pj[j] += __shfl_xor(pj[j], sft);
            }
        }
        if (l == 0) {
            float lg0 = wl0, lg1 = wl1;
#pragma unroll
            for (int j = 0; j < 10; j++) {
                float dist = -2.f * dj[j] + gn + pj[j];
                float sv = logf((dist + 1.0f) / (dist + 1e-4f));
                out_dist[g * 10 + j] = dist;
                out_sim[g * 10 + j] = sv;
                lg0 = fmaf(Wlast[j], sv, lg0);
                lg1 = fmaf(Wlast[138 + j], sv, lg1);
            }
            out_logits[2 * g] = lg0; out_logits[2 * g + 1] = lg1;
            float m = fmaxf(lg0, lg1);
            float e0 = expf(lg0 - m), e1 = expf(lg1 - m);
            float iv = 1.f / (e0 + e1);
            out_probs[2 * g] = e0 * iv; out_probs[2 * g + 1] = e1 * iv;
        }
    }
}

// ---------------- adjacency + last-block final scalars ----------------
__global__ __launch_bounds__(256) void adj_kernel(const float* __restrict__ assn,
                                                  const int* __restrict__ src,
                                                  const int* __restrict__ dst,
                                                  float* __restrict__ adjp,
                                                  const float* __restrict__ kpart,
                                                  float* __restrict__ out,
                                                  int* __restrict__ cnt) {
    int t = threadIdx.x;
    float p00 = 0.f, p01 = 0.f, p10 = 0.f, p11 = 0.f;
    for (int e = blockIdx.x * 256 + t; e < NE; e += ADJ_BLOCKS * 256) {
        float2 a = *(const float2*)(assn + 2 * (size_t)src[e]);
        float2 b = *(const float2*)(assn + 2 * (size_t)dst[e]);
        p00 += a.x * b.x; p01 += a.x * b.y; p10 += a.y * b.x; p11 += a.y * b.y;
    }
    __shared__ float s0[256], s1[256], s2[256], s3[256];
    s0[t] = p00; s1[t] = p01; s2[t] = p10; s3[t] = p11;
    __syncthreads();
    for (int s = 128; s > 0; s >>= 1) {
        if (t < s) { s0[t] += s0[t + s]; s1[t] += s1[t + s]; s2[t] += s2[t + s]; s3[t] += s3[t + s]; }
        __syncthreads();
    }
    if (t == 0) {
        float4* o = (float4*)(adjp + 4 * (size_t)blockIdx.x);
        *o = make_float4(s0[0], s1[0], s2[0], s3[0]);
    }

    if (!last_block(cnt, ADJ_BLOCKS)) return;

    __syncthreads();   // reuse LDS
    float k1 = 0.f, k2 = 0.f, a0 = 0.f, a1 = 0.f, a2 = 0.f, a3 = 0.f;
    for (int i = t; i < NOISY_BLOCKS; i += 256) {
        float2 v = ((const float2*)kpart)[i];
        k1 += v.x; k2 += v.y;
    }
    for (int i = t; i < ADJ_BLOCKS; i += 256) {
        float4 v = ((const float4*)adjp)[i];
        a0 += v.x; a1 += v.y; a2 += v.z; a3 += v.w;
    }
    __shared__ float sh[6 * 256];
    sh[t] = k1; sh[256 + t] = k2; sh[512 + t] = a0;
    sh[768 + t] = a1; sh[1024 + t] = a2; sh[1280 + t] = a3;
    __syncthreads();
    for (int s = 128; s > 0; s >>= 1) {
        if (t < s) {
#pragma unroll
            for (int v = 0; v < 6; v++) sh[v * 256 + t] += sh[v * 256 + t + s];
        }
        __syncthreads();
    }
    if (t == 0) {
        float kl = 0.5f / ((float)NND * (float)DIM) * sh[0] + (1.0f / (float)DIM) * sh[256];
        out[16896] = kl;
        float a00 = sh[512], a01 = sh[768], a10 = sh[1024], a11 = sh[1280];
        float r0 = fmaxf(fabsf(a00) + fabsf(a01), 1e-12f);
        float r1 = fmaxf(fabsf(a10) + fabsf(a11), 1e-12f);
        float d0 = a00 / r0 - 1.f, d1 = a11 / r1 - 1.f;
        out[16897] = 0.5f * (d0 * d0 + d1 * d1);
    }
}

// ---------------- launcher ----------------
extern "C" void kernel_launch(void* const* d_in, const int* in_sizes, int n_in,
                              void* d_out, int out_size, void* d_ws, size_t ws_size,
                              hipStream_t stream) {
    (void)in_sizes; (void)n_in; (void)out_size; (void)ws_size;
    const float* x     = (const float*)d_in[0];
    const int*   ei    = (const int*)d_in[1];
    const int*   batch = (const int*)d_in[2];
    const float* W0a   = (const float*)d_in[3];
    const float* W0b   = (const float*)d_in[4];
    const float* g0    = (const float*)d_in[5];
    const float* b0    = (const float*)d_in[6];
    const float* W1a   = (const float*)d_in[7];
    const float* W1b   = (const float*)d_in[8];
    const float* g1    = (const float*)d_in[9];
    const float* b1    = (const float*)d_in[10];
    const float* Wm0   = (const float*)d_in[11];
    const float* bm0   = (const float*)d_in[12];
    const float* gm    = (const float*)d_in[13];
    const float* bm    = (const float*)d_in[14];
    const float* Wm1   = (const float*)d_in[15];
    const float* bm1   = (const float*)d_in[16];
    const float* Wfc1  = (const float*)d_in[17];
    const float* bfc1  = (const float*)d_in[18];
    const float* Wfc2  = (const float*)d_in[19];
    const float* bfc2  = (const float*)d_in[20];
    const float* protos= (const float*)d_in[21];
    const float* Wlast = (const float*)d_in[22];
    const int* src = ei;
    const int* dst = ei + NE;
    float* out = (float*)d_out;

    // f32 region
    float* nodef = (float*)d_ws;                    // N*128 (node_feature, f32)
    float* abuf  = nodef + (size_t)NND * DIM;       // N*128 (noisy)
    float* assn  = abuf + (size_t)NND * DIM;        // N*2
    float* cs    = assn + (size_t)NND * 2;          // 1024
    float* kpart = cs + 1024;                       // NOISY_BLOCKS*2
    float* adjp  = kpart + NOISY_BLOCKS * 2;        // ADJ_BLOCKS*4
    float* sscr  = adjp + ADJ_BLOCKS * 4;           // SROWS*256
    float* gpart = sscr + (size_t)SROWS * 256;      // NG*EMB_SPLIT*DIM
    // bf16 region
    ushort* aggH = (ushort*)(gpart + NG * EMB_SPLIT * DIM);  // N*128
    ushort* xnfH = aggH + (size_t)NND * DIM;                 // N*128
    ushort* tBH  = xnfH + (size_t)NND * DIM;                 // N*128 (a1)
    ushort* tAH  = tBH + (size_t)NND * DIM;                  // N*128
    ushort* ndH  = tAH + (size_t)NND * DIM;                  // N*128
    ushort* t5H  = ndH + (size_t)NND * DIM;                  // N*64
    // int region
    int* deg    = (int*)(t5H + (size_t)NND * HID);
    int* offv   = deg + NND;
    int* cursor = offv + NND + 1;
    int* elist  = cursor + NND;
    int* gstart = elist + NE;
    int* bsum   = gstart + NG + 1;
    int* boff   = bsum + NSCB;
    int* cnt    = boff + NSCB;        // 160 ints: [0..5] kernel counters, [6..133] per-graph

    // threefry keys on host
    uint32_t kg0 = 0u, kg1 = 0u; threefry2x32(0u, 42u, kg0, kg1);  // ctr (0,0)
    uint32_t kn0 = 0u, kn1 = 1u; threefry2x32(0u, 42u, kn0, kn1);  // ctr (0,1)

    const int GAB = NND / 4;
    const size_t GIN_LDS = 2u * 128u * 136u * sizeof(ushort);   // 69632 B
    dim3 g2(SROWS, 2), g1x(SROWS, 1);

    // 1: convert x + gstart + zero deg/counters
    cvt_fused_kernel<<<CVB + 2 * NSCB, 256, 0, stream>>>(x, xnfH, batch, gstart, deg, cnt);
    // 2-5: CSR
    hist_kernel<<<(NE + 255) / 256, 256, 0, stream>>>(dst, deg);
    scan_bsum_kernel<<<NSCB, 256, 0, stream>>>(deg, bsum, boff, offv, cnt + 5);
    scan_final_kernel<<<NSCB, 256, 0, stream>>>(deg, boff, offv, cursor);
    build_kernel<<<(NE + 255) / 256, 256, 0, stream>>>(src, dst, cursor, elist);

    // 6-7: GIN layer 1
    gather_kernel<0><<<GAB, 256, 0, stream>>>(xnfH, offv, elist, aggH, nullptr);
    gin2_kernel<<<SROWS, 256, GIN_LDS, stream>>>(aggH, W0a, W0b, tAH, sscr, g0, b0, cs + 0, cnt + 0, NND);

    // 8-9: GIN layer 2 (gather applies affine0+relu)
    gather_kernel<1><<<GAB, 256, 0, stream>>>(tAH, offv, elist, aggH, cs + 0);
    gin2_kernel<<<SROWS, 256, GIN_LDS, stream>>>(aggH, W1a, W1b, tAH, sscr, g1, b1, cs + 256, cnt + 1, NND);

    // 10-12: bottleneck MLP
    mgemm_kernel<128,64,0,1,1,0><<<g1x, 256, 0, stream>>>(tAH, Wm0, bm0, nullptr, t5H, sscr,
        cs + 256, cs + 384, gm, bm, cs + 512, cnt + 2, 1, NND);
    mgemm_kernel<64,128,0,1,2,2><<<g2, 256, 0, stream>>>(t5H, Wm1, bm1, nodef, ndH, sscr,
        cs + 512, cs + 576, nullptr, nullptr, cs + 640, cnt + 3, 0, NND);   // node_feature + raw stats
    mgemm_kernel<128,128,2,0,0,0><<<g2, 256, 0, stream>>>(ndH, Wfc1, bfc1, nullptr, tBH, nullptr,
        nullptr, nullptr, nullptr, nullptr, nullptr, nullptr, 0, NND);      // a1 bf16

    // 13: assign + noisy + kl partials
    noisy_kernel<<<NOISY_BLOCKS, 256, 0, stream>>>(nodef, tBH, Wfc2, bfc2, cs + 640,
                                                   abuf, assn, kpart, kg0, kg1, kn0, kn1);

    // 14: graph pooling + head (per-graph last-block)
    emb_head_kernel<<<NG * EMB_SPLIT, 128, 0, stream>>>(abuf, gstart, gpart, protos, Wlast,
        out, out + 256, out + 512, out + 16898, out + 18178, cnt + 6);

    // 15: adjacency + final scalars
    adj_kernel<<<ADJ_BLOCKS, 256, 0, stream>>>(assn, src, dst, adjp, kpart, out, cnt + 4);
}

// Round 14
// 304.534 us; speedup vs baseline: 2.3256x; 2.3256x over previous
//
#include <hip/hip_runtime.h>
#include <hip/hip_bf16.h>
#include <stdint.h>

#define NND 40000
#define NE  640000
#define NG  128
#define DIM 128
#define HID 64
#define ADJ_BLOCKS 640
#define NOISY_BLOCKS 5000   // NND*32/256
#define NSCB ((NND + 255) / 256)   // 157 scan blocks
#define EMB_SPLIT 8
#define SROWS 313            // gemm row blocks (128 rows each) = stats rows
#define CVB 2500             // convert blocks

typedef short v8s __attribute__((ext_vector_type(8)));
typedef float v4f __attribute__((ext_vector_type(4)));

// ---------------- threefry2x32 (20 rounds), JAX-compatible ----------------
__host__ __device__ inline uint32_t rotl32(uint32_t v, uint32_t r) {
    return (v << r) | (v >> (32u - r));
}

__host__ __device__ inline void threefry2x32(uint32_t k0, uint32_t k1,
                                             uint32_t& x0, uint32_t& x1) {
    uint32_t k2 = k0 ^ k1 ^ 0x1BD11BDAu;
    x0 += k0; x1 += k1;
#define TFR(r) { x0 += x1; x1 = rotl32(x1, r); x1 ^= x0; }
    TFR(13u) TFR(15u) TFR(26u) TFR(6u)
    x0 += k1; x1 += k2 + 1u;
    TFR(17u) TFR(29u) TFR(16u) TFR(24u)
    x0 += k2; x1 += k0 + 2u;
    TFR(13u) TFR(15u) TFR(26u) TFR(6u)
    x0 += k0; x1 += k1 + 3u;
    TFR(17u) TFR(29u) TFR(16u) TFR(24u)
    x0 += k1; x1 += k2 + 4u;
    TFR(13u) TFR(15u) TFR(26u) TFR(6u)
    x0 += k2; x1 += k0 + 5u;
#undef TFR
}

__device__ inline float rbits_u01(uint32_t k0, uint32_t k1, uint32_t idx) {
    uint32_t x0 = 0u, x1 = idx;
    threefry2x32(k0, k1, x0, x1);
    uint32_t b = x0 ^ x1;
    return __uint_as_float((b >> 9) | 0x3f800000u) - 1.0f;
}

__device__ inline ushort bfbits(float a) {
    __hip_bfloat16 h = __float2bfloat16(a);
    return *(ushort*)&h;
}

__device__ inline uint32_t bfpack(float a, float b) {
    return (uint32_t)bfbits(a) | ((uint32_t)bfbits(b) << 16);
}

#define UNPACK8(v, f)                                                     \
    f[0] = __uint_as_float((v).x << 16); f[1] = __uint_as_float((v).x & 0xffff0000u); \
    f[2] = __uint_as_float((v).y << 16); f[3] = __uint_as_float((v).y & 0xffff0000u); \
    f[4] = __uint_as_float((v).z << 16); f[5] = __uint_as_float((v).z & 0xffff0000u); \
    f[6] = __uint_as_float((v).w << 16); f[7] = __uint_as_float((v).w & 0xffff0000u);

// ---------------- fused convert: x->bf16, gstart, zero deg (fence-free) ----------
__global__ __launch_bounds__(256) void cvt_fused_kernel(const float* __restrict__ in,
                                                        ushort* __restrict__ outh,
                                                        const int* __restrict__ batch,
                                                        int* __restrict__ gstart,
                                                        int* __restrict__ deg) {
    int blk = blockIdx.x, t = threadIdx.x;
    if (blk < CVB) {
        int i = blk * 256 + t;
        const float4* p = (const float4*)in + (size_t)i * 2;
        float4 a = p[0], b = p[1];
        uint4 o;
        o.x = bfpack(a.x, a.y); o.y = bfpack(a.z, a.w);
        o.z = bfpack(b.x, b.y); o.w = bfpack(b.z, b.w);
        *(uint4*)(outh + (size_t)i * 8) = o;
    } else if (blk < CVB + NSCB) {
        int i = (blk - CVB) * 256 + t;
        if (i < NND) {
            int b = batch[i];
            int prev = (i == 0) ? -1 : batch[i - 1];
            for (int g = prev + 1; g <= b; g++) gstart[g] = i;
            if (i == NND - 1)
                for (int g = b + 1; g <= NG; g++) gstart[g] = NND;
        }
    } else {
        int i = (blk - CVB - NSCB) * 256 + t;
        if (i < NND) deg[i] = 0;
    }
}

// ---------------- CSR build ----------------
__global__ __launch_bounds__(256) void hist_kernel(const int* __restrict__ dst,
                                                   int* __restrict__ deg) {
    int e = blockIdx.x * 256 + threadIdx.x;
    if (e < NE) atomicAdd(&deg[dst[e]], 1);
}

__global__ __launch_bounds__(256) void scan_bsum_kernel(const int* __restrict__ deg,
                                                        int* __restrict__ bsum) {
    int t = threadIdx.x;
    int i = blockIdx.x * 256 + t;
    int v = (i < NND) ? deg[i] : 0;
    __shared__ int sh[256];
    sh[t] = v;
    __syncthreads();
#pragma unroll
    for (int s = 128; s > 0; s >>= 1) {
        if (t < s) sh[t] += sh[t + s];
        __syncthreads();
    }
    if (t == 0) bsum[blockIdx.x] = sh[0];
}

__global__ __launch_bounds__(256) void scan_boff_kernel(const int* __restrict__ bsum,
                                                        int* __restrict__ boff,
                                                        int* __restrict__ offv) {
    int t = threadIdx.x;
    int v = (t < NSCB) ? bsum[t] : 0;
    __shared__ int sh[256];
    sh[t] = v;
    __syncthreads();
    for (int d = 1; d < 256; d <<= 1) {
        int u = (t >= d) ? sh[t - d] : 0;
        __syncthreads();
        sh[t] += u;
        __syncthreads();
    }
    if (t < NSCB) boff[t] = sh[t] - v;   // exclusive
    if (t == NSCB - 1) offv[NND] = sh[t];
}

__global__ __launch_bounds__(256) void scan_final_kernel(const int* __restrict__ deg,
                                                         const int* __restrict__ boff,
                                                         int* __restrict__ offv,
                                                         int* __restrict__ cursor) {
    int t = threadIdx.x;
    int i = blockIdx.x * 256 + t;
    int v = (i < NND) ? deg[i] : 0;
    __shared__ int sh[256];
    sh[t] = v;
    __syncthreads();
    for (int d = 1; d < 256; d <<= 1) {
        int u = (t >= d) ? sh[t - d] : 0;
        __syncthreads();
        sh[t] += u;
        __syncthreads();
    }
    int off = boff[blockIdx.x] + sh[t] - v;
    if (i < NND) { offv[i] = off; cursor[i] = off; }
}

__global__ __launch_bounds__(256) void build_kernel(const int* __restrict__ src,
                                                    const int* __restrict__ dst,
                                                    int* __restrict__ cursor,
                                                    int* __restrict__ elist) {
    int e = blockIdx.x * 256 + threadIdx.x;
    if (e < NE) {
        int p = atomicAdd(&cursor[dst[e]], 1);
        elist[p] = src[e];
    }
}

// ---------------- gather: wave/node, 4 edge-slots x 16 col-slots; bf16 in/out.
// AFF=1: apply per-column affine+relu to each loaded element (BN fold).
template <int AFF>
__global__ __launch_bounds__(256) void gather_kernel(const ushort* __restrict__ feath,
                                                     const int* __restrict__ offv,
                                                     const int* __restrict__ elist,
                                                     ushort* __restrict__ aggh,
                                                     const float* __restrict__ cs) {
    int gt = blockIdx.x * 256 + threadIdx.x;
    int n = gt >> 6;
    int lane = threadIdx.x & 63;
    int e = lane >> 4, c = lane & 15;
    const uint4* F = (const uint4*)feath;
    int o0 = offv[n], o1 = offv[n + 1];

    float sc[8], sh[8];
    if (AFF) {
#pragma unroll
        for (int j = 0; j < 8; j++) {
            sc[j] = cs[c * 8 + j];
            sh[j] = cs[DIM + c * 8 + j];
        }
    }

    float acc[8];
    if (e == 0) {
        uint4 v = F[(size_t)n * 16 + c];
        UNPACK8(v, acc)
        if (AFF) {
#pragma unroll
            for (int j = 0; j < 8; j++) acc[j] = fmaxf(fmaf(acc[j], sc[j], sh[j]), 0.f);
        }
    } else {
#pragma unroll
        for (int j = 0; j < 8; j++) acc[j] = 0.f;
    }

    for (int i = o0 + e; i < o1; i += 4) {
        int s = elist[i];
        uint4 v = F[(size_t)s * 16 + c];
        float f[8];
        UNPACK8(v, f)
        if (AFF) {
#pragma unroll
            for (int j = 0; j < 8; j++) f[j] = fmaxf(fmaf(f[j], sc[j], sh[j]), 0.f);
        }
#pragma unroll
        for (int j = 0; j < 8; j++) acc[j] += f[j];
    }

#pragma unroll
    for (int j = 0; j < 8; j++) {
        acc[j] += __shfl_xor(acc[j], 16);
        acc[j] += __shfl_xor(acc[j], 32);
    }

    uint32_t wv;
    if (e == 0)      wv = bfpack(acc[0], acc[1]);
    else if (e == 1) wv = bfpack(acc[2], acc[3]);
    else if (e == 2) wv = bfpack(acc[4], acc[5]);
    else             wv = bfpack(acc[6], acc[7]);
    ((uint32_t*)aggh)[(size_t)n * 64 + c * 4 + e] = wv;
}

// ---------------- fused GIN double-GEMM (stats partials only, no fences) ---------
__global__ __launch_bounds__(256) void gin2_kernel(const ushort* __restrict__ Ah,
                                                   const float* __restrict__ Wa,
                                                   const float* __restrict__ Wb,
                                                   ushort* __restrict__ outh,
                                                   float* __restrict__ sscr,
                                                   int nrows) {
    constexpr int K = 128, KP = 136;
    extern __shared__ ushort lds[];
    ushort* B1 = lds;                 // KP*128
    ushort* B2 = lds + 128 * KP;      // KP*128

    const int t = threadIdx.x;
    const int w = t >> 6, l = t & 63;
    const int lm = l & 15, lk = l >> 4;
    const int row0 = blockIdx.x * 128 + w * 32;

    uint4 areg[2][4];
#pragma unroll
    for (int rf = 0; rf < 2; rf++) {
        int r = row0 + rf * 16 + lm;
        const ushort* ap = Ah + (size_t)min(r, nrows - 1) * K + lk * 8;
#pragma unroll
        for (int kc = 0; kc < 4; kc++)
            areg[rf][kc] = *(const uint4*)(ap + kc * 32);
    }

    for (int idx = t; idx < K * K; idx += 256) {
        int k = idx >> 7, c = idx & 127;
        B1[c * KP + k] = bfbits(Wa[idx]);
        B2[c * KP + k] = bfbits(Wb[idx]);
    }
    __syncthreads();

    v4f acc[2][8];
#pragma unroll
    for (int i = 0; i < 2; i++)
#pragma unroll
        for (int j = 0; j < 8; j++) acc[i][j] = (v4f){0.f, 0.f, 0.f, 0.f};

#pragma unroll
    for (int kc = 0; kc < 4; kc++) {
        v8s a0 = *(const v8s*)&areg[0][kc];
        v8s a1 = *(const v8s*)&areg[1][kc];
#pragma unroll
        for (int nc = 0; nc < 8; nc++) {
            v8s bfr = *(const v8s*)(B1 + (nc * 16 + lm) * KP + kc * 32 + lk * 8);
            acc[0][nc] = __builtin_amdgcn_mfma_f32_16x16x32_bf16(a0, bfr, acc[0][nc], 0, 0, 0);
            acc[1][nc] = __builtin_amdgcn_mfma_f32_16x16x32_bf16(a1, bfr, acc[1][nc], 0, 0, 0);
        }
    }

    __syncthreads();
#pragma unroll
    for (int rf = 0; rf < 2; rf++)
#pragma unroll
        for (int nc = 0; nc < 8; nc++)
#pragma unroll
            for (int reg = 0; reg < 4; reg++) {
                int r = w * 32 + rf * 16 + lk * 4 + reg;
                int c = nc * 16 + lm;
                B1[r * KP + c] = bfbits(fmaxf(acc[rf][nc][reg], 0.f));
            }
    __syncthreads();

    v4f acc2[2][8];
#pragma unroll
    for (int i = 0; i < 2; i++)
#pragma unroll
        for (int j = 0; j < 8; j++) acc2[i][j] = (v4f){0.f, 0.f, 0.f, 0.f};

#pragma unroll
    for (int kc = 0; kc < 4; kc++) {
        v8s a0 = *(const v8s*)(B1 + (w * 32 + lm) * KP + kc * 32 + lk * 8);
        v8s a1 = *(const v8s*)(B1 + (w * 32 + 16 + lm) * KP + kc * 32 + lk * 8);
#pragma unroll
        for (int nc = 0; nc < 8; nc++) {
            v8s bfr = *(const v8s*)(B2 + (nc * 16 + lm) * KP + kc * 32 + lk * 8);
            acc2[0][nc] = __builtin_amdgcn_mfma_f32_16x16x32_bf16(a0, bfr, acc2[0][nc], 0, 0, 0);
            acc2[1][nc] = __builtin_amdgcn_mfma_f32_16x16x32_bf16(a1, bfr, acc2[1][nc], 0, 0, 0);
        }
    }

    float ps[8], pq[8];
#pragma unroll
    for (int nc = 0; nc < 8; nc++) { ps[nc] = 0.f; pq[nc] = 0.f; }

#pragma unroll
    for (int nc = 0; nc < 8; nc++) {
        int cg = nc * 16 + lm;
#pragma unroll
        for (int rf = 0; rf < 2; rf++)
#pragma unroll
            for (int reg = 0; reg < 4; reg++) {
                int rg = row0 + rf * 16 + lk * 4 + reg;
                if (rg < nrows) {
                    float v = fmaxf(acc2[rf][nc][reg], 0.f);
                    outh[(size_t)rg * K + cg] = bfbits(v);
                    ps[nc] += v; pq[nc] += v * v;
                }
            }
    }

    __syncthreads();
    float* scr = (float*)lds;
#pragma unroll
    for (int nc = 0; nc < 8; nc++) {
        ps[nc] += __shfl_xor(ps[nc], 16); ps[nc] += __shfl_xor(ps[nc], 32);
        pq[nc] += __shfl_xor(pq[nc], 16); pq[nc] += __shfl_xor(pq[nc], 32);
    }
    if (lk == 0) {
#pragma unroll
        for (int nc = 0; nc < 8; nc++) {
            scr[w * 128 + nc * 16 + lm]       = ps[nc];
            scr[512 + w * 128 + nc * 16 + lm] = pq[nc];
        }
    }
    __syncthreads();
    if (t < 128) {
        float s = scr[t] + scr[128 + t] + scr[256 + t] + scr[384 + t];
        float q = scr[512 + t] + scr[640 + t] + scr[768 + t] + scr[896 + t];
        sscr[(size_t)blockIdx.x * 256 + t]       = s;
        sscr[(size_t)blockIdx.x * 256 + 128 + t] = q;
    }
}

// ---------------- MFMA GEMM (single), stats partials only ----------------
template <int K, int M, int ACT, int STATS, int PRE, int OUTM>
__global__ __launch_bounds__(256) void mgemm_kernel(const ushort* __restrict__ Ah,
                                                    const float* __restrict__ W,
                                                    const float* __restrict__ bias,
                                                    float* __restrict__ outf,
                                                    ushort* __restrict__ outh,
                                                    float* __restrict__ sscr,
                                                    const float* __restrict__ pscale,
                                                    const float* __restrict__ pshift,
                                                    int nrows) {
    constexpr int KP  = K + 8;
    constexpr int NKC = K / 32;
    __shared__ __align__(16) ushort sW[64 * KP];

    const int t = threadIdx.x;
    const int w = t >> 6, l = t & 63;
    const int lm = l & 15, lk = l >> 4;
    const int col0 = blockIdx.y * 64;
    const int row0 = blockIdx.x * 128 + w * 32;

    for (int idx = t; idx < K * 64; idx += 256) {
        int k = idx >> 6, c = idx & 63;
        sW[c * KP + k] = bfbits(W[(size_t)k * M + col0 + c]);
    }

    uint4 areg[2][NKC];
#pragma unroll
    for (int rf = 0; rf < 2; rf++) {
        int r = row0 + rf * 16 + lm;
        const ushort* ap = Ah + (size_t)min(r, nrows - 1) * K + lk * 8;
#pragma unroll
        for (int kc = 0; kc < NKC; kc++)
            areg[rf][kc] = *(const uint4*)(ap + kc * 32);
    }

    __syncthreads();

    v4f acc[2][4];
#pragma unroll
    for (int i = 0; i < 2; i++)
#pragma unroll
        for (int j = 0; j < 4; j++) acc[i][j] = (v4f){0.f, 0.f, 0.f, 0.f};

#pragma unroll
    for (int kc = 0; kc < NKC; kc++) {
        v8s bfr[4];
#pragma unroll
        for (int nc = 0; nc < 4; nc++)
            bfr[nc] = *(const v8s*)(sW + (nc * 16 + lm) * KP + kc * 32 + lk * 8);

        v8s afr[2];
#pragma unroll
        for (int rf = 0; rf < 2; rf++) {
            if (PRE > 0) {
                int k0 = kc * 32 + lk * 8;
                float f[8];
                uint4 v = areg[rf][kc];
                UNPACK8(v, f)
                float4 s0 = *(const float4*)(pscale + k0);
                float4 s1 = *(const float4*)(pscale + k0 + 4);
                float4 h0 = *(const float4*)(pshift + k0);
                float4 h1 = *(const float4*)(pshift + k0 + 4);
                f[0] = fmaf(f[0], s0.x, h0.x); f[1] = fmaf(f[1], s0.y, h0.y);
                f[2] = fmaf(f[2], s0.z, h0.z); f[3] = fmaf(f[3], s0.w, h0.w);
                f[4] = fmaf(f[4], s1.x, h1.x); f[5] = fmaf(f[5], s1.y, h1.y);
                f[6] = fmaf(f[6], s1.z, h1.z); f[7] = fmaf(f[7], s1.w, h1.w);
                if (PRE == 2) {
#pragma unroll
                    for (int e2 = 0; e2 < 8; e2++) f[e2] = fmaxf(f[e2], 0.f);
                }
                v8s a;
#pragma unroll
                for (int e2 = 0; e2 < 8; e2++) a[e2] = (short)bfbits(f[e2]);
                afr[rf] = a;
            } else {
                afr[rf] = *(const v8s*)&areg[rf][kc];
            }
        }

#pragma unroll
        for (int rf = 0; rf < 2; rf++)
#pragma unroll
            for (int nc = 0; nc < 4; nc++)
                acc[rf][nc] = __builtin_amdgcn_mfma_f32_16x16x32_bf16(
                    afr[rf], bfr[nc], acc[rf][nc], 0, 0, 0);
    }

    float ps[4], pq[4];
#pragma unroll
    for (int nc = 0; nc < 4; nc++) { ps[nc] = 0.f; pq[nc] = 0.f; }

#pragma unroll
    for (int nc = 0; nc < 4; nc++) {
        int cg = col0 + nc * 16 + lm;
        float bv = bias ? bias[cg] : 0.f;
#pragma unroll
        for (int rf = 0; rf < 2; rf++) {
#pragma unroll
            for (int reg = 0; reg < 4; reg++) {
                int rg = row0 + rf * 16 + lk * 4 + reg;
                if (rg < nrows) {
                    float v = acc[rf][nc][reg] + bv;
                    if (ACT == 1) v = fmaxf(v, 0.f);
                    if (ACT == 2) v = tanhf(v);
                    if (OUTM != 0) outf[(size_t)rg * M + cg] = v;
                    if (OUTM != 1) outh[(size_t)rg * M + cg] = bfbits(v);
                    ps[nc] += v; pq[nc] += v * v;
                }
            }
        }
    }

    if (STATS) {
        __syncthreads();
        float* scr = (float*)sW;
#pragma unroll
        for (int nc = 0; nc < 4; nc++) {
            ps[nc] += __shfl_xor(ps[nc], 16); ps[nc] += __shfl_xor(ps[nc], 32);
            pq[nc] += __shfl_xor(pq[nc], 16); pq[nc] += __shfl_xor(pq[nc], 32);
        }
        if (lk == 0) {
#pragma unroll
            for (int nc = 0; nc < 4; nc++) {
                scr[w * 64 + nc * 16 + lm]       = ps[nc];
                scr[256 + w * 64 + nc * 16 + lm] = pq[nc];
            }
        }
        __syncthreads();
        if (t < 64) {
            float s = scr[t] + scr[64 + t] + scr[128 + t] + scr[192 + t];
            float q = scr[256 + t] + scr[320 + t] + scr[384 + t] + scr[448 + t];
            sscr[(size_t)blockIdx.x * 2 * M + col0 + t]     = s;
            sscr[(size_t)blockIdx.x * 2 * M + M + col0 + t] = q;
        }
    }
}

// reduce stats partials; affine=1: write (scale, shift); else raw (sum,sumsq).
template <int M>
__global__ __launch_bounds__(256) void stats_reduce_kernel(const float* __restrict__ sscr,
                                                           int nblk,
                                                           const float* __restrict__ g,
                                                           const float* __restrict__ b,
                                                           float* __restrict__ cs,
                                                           int affine) {
    const int cols = 2 * M;
    const int t = threadIdx.x;
    const int c = blockIdx.x * 8 + (t & 7);
    const int rl = t >> 3;
    float s = 0.f, q = 0.f;
    for (int r = rl; r < nblk; r += 32) {
        s += sscr[(size_t)r * cols + c];
        q += sscr[(size_t)r * cols + M + c];
    }
    __shared__ float shs[256], shq[256];
    shs[t] = s; shq[t] = q;
    __syncthreads();
#pragma unroll
    for (int st = 128; st >= 8; st >>= 1) {
        if (t < st) { shs[t] += shs[t + st]; shq[t] += shq[t + st]; }
        __syncthreads();
    }
    if (t < 8) {
        float ss = shs[t], qq = shq[t];
        if (affine) {
            const float invN = 1.0f / (float)NND;
            float mu = ss * invN;
            float var = fmaxf(qq * invN - mu * mu, 0.f);
            float sc = g[c] * rsqrtf(var + 1e-5f);
            cs[c] = sc;
            cs[M + c] = b[c] - mu * sc;
        } else {
            cs[c] = ss;
            cs[M + c] = qq;
        }
    }
}

// ---------------- fused assign + noisy + kl partials (fence-free) ----------------
__global__ __launch_bounds__(256) void noisy_kernel(const float* __restrict__ nfeat,
                                                    const ushort* __restrict__ a1h,
                                                    const float* __restrict__ Wfc2,
                                                    const float* __restrict__ bfc2,
                                                    const float* __restrict__ cs3,
                                                    float* __restrict__ noisy,
                                                    float* __restrict__ assn,
                                                    float* __restrict__ kpart,
                                                    uint32_t kg0, uint32_t kg1,
                                                    uint32_t kn0, uint32_t kn1) {
    __shared__ float wsh[DIM * 2];
    int t = threadIdx.x;
    wsh[t] = Wfc2[t];
    __syncthreads();

    int gt = blockIdx.x * 256 + t;
    int n = gt >> 5, c4 = t & 31, d = c4 * 4;

    float d0 = 0.f, d1 = 0.f;
    {
        uint2 av = *(const uint2*)(a1h + (size_t)n * DIM + d);
        float a0 = __uint_as_float(av.x << 16);
        float a1 = __uint_as_float(av.x & 0xffff0000u);
        float a2 = __uint_as_float(av.y << 16);
        float a3 = __uint_as_float(av.y & 0xffff0000u);
        d0 = a0 * wsh[2 * d] + a1 * wsh[2 * (d + 1)] + a2 * wsh[2 * (d + 2)] + a3 * wsh[2 * (d + 3)];
        d1 = a0 * wsh[2 * d + 1] + a1 * wsh[2 * (d + 1) + 1] + a2 * wsh[2 * (d + 2) + 1] + a3 * wsh[2 * (d + 3) + 1];
    }
#pragma unroll
    for (int s = 16; s > 0; s >>= 1) {
        d0 += __shfl_xor(d0, s);
        d1 += __shfl_xor(d1, s);
    }

    float la0 = 0.f, la1 = 0.f;
    if (c4 == 0) {
        float dd0 = d0 + bfc2[0], dd1 = d1 + bfc2[1];
        float m = fmaxf(dd0, dd1);
        float e0 = expf(dd0 - m), e1 = expf(dd1 - m);
        float inv = 1.f / (e0 + e1);
        float as0 = e0 * inv, as1 = e1 * inv;
        assn[2 * n] = as0; assn[2 * n + 1] = as1;

        float uf0 = rbits_u01(kg0, kg1, (uint32_t)(2 * n));
        float uf1 = rbits_u01(kg0, kg1, (uint32_t)(2 * n + 1));
        float u0 = fmaxf(1e-10f, uf0 + 1e-10f);
        float u1 = fmaxf(1e-10f, uf1 + 1e-10f);
        float gu0 = -logf(-logf(u0));
        float gu1 = -logf(-logf(u1));
        float y0 = as0 + gu0, y1 = as1 + gu1;
        float mm = fmaxf(y0, y1);
        float f0 = expf(y0 - mm), f1 = expf(y1 - mm);
        float iv = 1.f / (f0 + f1);
        la0 = f0 * iv; la1 = f1 * iv;
    }
    la0 = __shfl(la0, 0, 32);
    la1 = __shfl(la1, 0, 32);

    const float invN = 1.0f / (float)NND;
    float4 xv = *(const float4*)(nfeat + (size_t)n * DIM + d);
    float xa[4] = {xv.x, xv.y, xv.z, xv.w};
    float t1 = 0.f, t2 = 0.f, o[4];
#pragma unroll
    for (int j = 0; j < 4; j++) {
        float mu = cs3[d + j] * invN;
        float q = cs3[DIM + d + j];
        float var1 = fmaxf(q - (float)NND * mu * mu, 0.f) / (float)(NND - 1);
        float sd = sqrtf(var1);
        float r = rbits_u01(kn0, kn1, (uint32_t)(n * DIM + d + j));
        float nm = la0 * xa[j] + la1 * mu;
        float ns = la1 * sd;
        o[j] = fmaf(r, ns, nm);
        float inv = 1.0f / (sd + 1e-7f);
        float z1 = ns * inv;            t1 += z1 * z1;
        float z2 = (nm - mu) * inv;     t2 += z2 * z2;
    }
    *(float4*)(noisy + (size_t)n * DIM + d) = make_float4(o[0], o[1], o[2], o[3]);

    __shared__ float s1[256], s2[256];
    s1[t] = t1; s2[t] = t2;
    __syncthreads();
    for (int s = 128; s > 0; s >>= 1) {
        if (t < s) { s1[t] += s1[t + s]; s2[t] += s2[t + s]; }
        __syncthreads();
    }
    if (t == 0) { kpart[2 * blockIdx.x] = s1[0]; kpart[2 * blockIdx.x + 1] = s2[0]; }
}

// ---------------- graph pooling partials ----------------
__global__ __launch_bounds__(128) void graph_emb_part_kernel(const float* __restrict__ noisy,
                                                             const int* __restrict__ gstart,
                                                             float* __restrict__ gpart) {
    int g = blockIdx.x / EMB_SPLIT;
    int sidx = blockIdx.x % EMB_SPLIT;
    int c = threadIdx.x;
    int s = gstart[g], e = gstart[g + 1];
    int len = e - s;
    int chunk = (len + EMB_SPLIT - 1) / EMB_SPLIT;
    int r0 = s + sidx * chunk;
    int r1 = min(r0 + chunk, e);
    float acc = 0.f;
    for (int r = r0; r < r1; r++) acc += noisy[(size_t)r * DIM + c];
    gpart[((size_t)g * EMB_SPLIT + sidx) * DIM + c] = acc;
}

// ---------------- merged emb reduce + head (ordinary launch, no fence) ----------
__global__ __launch_bounds__(128) void emb_head_kernel(const float* __restrict__ gpart,
                                                       const int* __restrict__ gstart,
                                                       const float* __restrict__ protos,
                                                       const float* __restrict__ Wlast,
                                                       float* __restrict__ out_logits,
                                                       float* __restrict__ out_probs,
                                                       float* __restrict__ emb_out,
                                                       float* __restrict__ out_sim,
                                                       float* __restrict__ out_dist) {
    int g = blockIdx.x, c = threadIdx.x;
    float tot = 0.f;
#pragma unroll
    for (int si = 0; si < EMB_SPLIT; si++)
        tot += gpart[((size_t)g * EMB_SPLIT + si) * DIM + c];
    float cntf = (float)(gstart[g + 1] - gstart[g]);
    float ev = tot / fmaxf(cntf, 1.f);
    emb_out[(size_t)g * DIM + c] = ev;

    __shared__ float se[DIM];
    se[c] = ev;
    __syncthreads();

    if (c < 64) {
        int l = c;
        float ge0 = se[l], ge1 = se[l + 64];
        float gn = ge0 * ge0 + ge1 * ge1;
        float dj[10], pj[10];
#pragma unroll
        for (int j = 0; j < 10; j++) {
            float pa = protos[j * DIM + l], pb = protos[j * DIM + l + 64];
            dj[j] = ge0 * pa + ge1 * pb;
            pj[j] = pa * pa + pb * pb;
        }
        float wl0 = ge0 * Wlast[10 + l] + ge1 * Wlast[10 + l + 64];
        float wl1 = ge0 * Wlast[138 + 10 + l] + ge1 * Wlast[138 + 10 + l + 64];
#pragma unroll
        for (int sft = 32; sft > 0; sft >>= 1) {
            gn += __shfl_xor(gn, sft);
            wl0 += __shfl_xor(wl0, sft);
            wl1 += __shfl_xor(wl1, sft);
#pragma unroll
            for (int j = 0; j < 10; j++) {
                dj[j] += __shfl_xor(dj[j], sft);
                pj[j] += __shfl_xor(pj[j], sft);
            }
        }
        if (l == 0) {
            float lg0 = wl0, lg1 = wl1;
#pragma unroll
            for (int j = 0; j < 10; j++) {
                float dist = -2.f * dj[j] + gn + pj[j];
                float sv = logf((dist + 1.0f) / (dist + 1e-4f));
                out_dist[g * 10 + j] = dist;
                out_sim[g * 10 + j] = sv;
                lg0 = fmaf(Wlast[j], sv, lg0);
                lg1 = fmaf(Wlast[138 + j], sv, lg1);
            }
            out_logits[2 * g] = lg0; out_logits[2 * g + 1] = lg1;
            float m = fmaxf(lg0, lg1);
            float e0 = expf(lg0 - m), e1 = expf(lg1 - m);
            float iv = 1.f / (e0 + e1);
            out_probs[2 * g] = e0 * iv; out_probs[2 * g + 1] = e1 * iv;
        }
    }
}

// ---------------- adjacency partials ----------------
__global__ __launch_bounds__(256) void adj_kernel(const float* __restrict__ assn,
                                                  const int* __restrict__ src,
                                                  const int* __restrict__ dst,
                                                  float* __restrict__ adjp) {
    int t = threadIdx.x;
    float p00 = 0.f, p01 = 0.f, p10 = 0.f, p11 = 0.f;
    for (int e = blockIdx.x * 256 + t; e < NE; e += ADJ_BLOCKS * 256) {
        float2 a = *(const float2*)(assn + 2 * (size_t)src[e]);
        float2 b = *(const float2*)(assn + 2 * (size_t)dst[e]);
        p00 += a.x * b.x; p01 += a.x * b.y; p10 += a.y * b.x; p11 += a.y * b.y;
    }
    __shared__ float s0[256], s1[256], s2[256], s3[256];
    s0[t] = p00; s1[t] = p01; s2[t] = p10; s3[t] = p11;
    __syncthreads();
    for (int s = 128; s > 0; s >>= 1) {
        if (t < s) { s0[t] += s0[t + s]; s1[t] += s1[t + s]; s2[t] += s2[t + s]; s3[t] += s3[t + s]; }
        __syncthreads();
    }
    if (t == 0) {
        float4* o = (float4*)(adjp + 4 * (size_t)blockIdx.x);
        *o = make_float4(s0[0], s1[0], s2[0], s3[0]);
    }
}

// ---------------- final scalars ----------------
__global__ __launch_bounds__(256) void final_scalar_kernel(const float* __restrict__ kpart,
                                                           const float* __restrict__ adjp,
                                                           float* __restrict__ out) {
    __shared__ float sh[6 * 256];
    int t = threadIdx.x;
    float k1 = 0.f, k2 = 0.f, a0 = 0.f, a1 = 0.f, a2 = 0.f, a3 = 0.f;
    for (int i = t; i < NOISY_BLOCKS; i += 256) {
        float2 v = ((const float2*)kpart)[i];
        k1 += v.x; k2 += v.y;
    }
    for (int i = t; i < ADJ_BLOCKS; i += 256) {
        float4 v = ((const float4*)adjp)[i];
        a0 += v.x; a1 += v.y; a2 += v.z; a3 += v.w;
    }
    sh[t] = k1; sh[256 + t] = k2; sh[512 + t] = a0;
    sh[768 + t] = a1; sh[1024 + t] = a2; sh[1280 + t] = a3;
    __syncthreads();
    for (int s = 128; s > 0; s >>= 1) {
        if (t < s) {
#pragma unroll
            for (int v = 0; v < 6; v++) sh[v * 256 + t] += sh[v * 256 + t + s];
        }
        __syncthreads();
    }
    if (t == 0) {
        float kl = 0.5f / ((float)NND * (float)DIM) * sh[0] + (1.0f / (float)DIM) * sh[256];
        out[16896] = kl;
        float a00 = sh[512], a01 = sh[768], a10 = sh[1024], a11 = sh[1280];
        float r0 = fmaxf(fabsf(a00) + fabsf(a01), 1e-12f);
        float r1 = fmaxf(fabsf(a10) + fabsf(a11), 1e-12f);
        float d0 = a00 / r0 - 1.f, d1 = a11 / r1 - 1.f;
        out[16897] = 0.5f * (d0 * d0 + d1 * d1);
    }
}

// ---------------- launcher ----------------
extern "C" void kernel_launch(void* const* d_in, const int* in_sizes, int n_in,
                              void* d_out, int out_size, void* d_ws, size_t ws_size,
                              hipStream_t stream) {
    (void)in_sizes; (void)n_in; (void)out_size; (void)ws_size;
    const float* x     = (const float*)d_in[0];
    const int*   ei    = (const int*)d_in[1];
    const int*   batch = (const int*)d_in[2];
    const float* W0a   = (const float*)d_in[3];
    const float* W0b   = (const float*)d_in[4];
    const float* g0    = (const float*)d_in[5];
    const float* b0    = (const float*)d_in[6];
    const float* W1a   = (const float*)d_in[7];
    const float* W1b   = (const float*)d_in[8];
    const float* g1    = (const float*)d_in[9];
    const float* b1    = (const float*)d_in[10];
    const float* Wm0   = (const float*)d_in[11];
    const float* bm0   = (const float*)d_in[12];
    const float* gm    = (const float*)d_in[13];
    const float* bm    = (const float*)d_in[14];
    const float* Wm1   = (const float*)d_in[15];
    const float* bm1   = (const float*)d_in[16];
    const float* Wfc1  = (const float*)d_in[17];
    const float* bfc1  = (const float*)d_in[18];
    const float* Wfc2  = (const float*)d_in[19];
    const float* bfc2  = (const float*)d_in[20];
    const float* protos= (const float*)d_in[21];
    const float* Wlast = (const float*)d_in[22];
    const int* src = ei;
    const int* dst = ei + NE;
    float* out = (float*)d_out;

    // f32 region
    float* nodef = (float*)d_ws;                    // N*128 (node_feature, f32)
    float* abuf  = nodef + (size_t)NND * DIM;       // N*128 (noisy)
    float* assn  = abuf + (size_t)NND * DIM;        // N*2
    float* cs    = assn + (size_t)NND * 2;          // 1024
    float* kpart = cs + 1024;                       // NOISY_BLOCKS*2
    float* adjp  = kpart + NOISY_BLOCKS * 2;        // ADJ_BLOCKS*4
    float* sscr  = adjp + ADJ_BLOCKS * 4;           // SROWS*256
    float* gpart = sscr + (size_t)SROWS * 256;      // NG*EMB_SPLIT*DIM
    // bf16 region
    ushort* aggH = (ushort*)(gpart + NG * EMB_SPLIT * DIM);  // N*128
    ushort* xnfH = aggH + (size_t)NND * DIM;                 // N*128
    ushort* tBH  = xnfH + (size_t)NND * DIM;                 // N*128 (a1)
    ushort* tAH  = tBH + (size_t)NND * DIM;                  // N*128
    ushort* ndH  = tAH + (size_t)NND * DIM;                  // N*128
    ushort* t5H  = ndH + (size_t)NND * DIM;                  // N*64
    // int region
    int* deg    = (int*)(t5H + (size_t)NND * HID);
    int* offv   = deg + NND;
    int* cursor = offv + NND + 1;
    int* elist  = cursor + NND;
    int* gstart = elist + NE;
    int* bsum   = gstart + NG + 1;
    int* boff   = bsum + NSCB;

    // threefry keys on host
    uint32_t kg0 = 0u, kg1 = 0u; threefry2x32(0u, 42u, kg0, kg1);  // ctr (0,0)
    uint32_t kn0 = 0u, kn1 = 1u; threefry2x32(0u, 42u, kn0, kn1);  // ctr (0,1)

    const int GAB = NND / 4;
    const size_t GIN_LDS = 2u * 128u * 136u * sizeof(ushort);   // 69632 B
    dim3 g2(SROWS, 2), g1x(SROWS, 1);

    // 1: convert x + gstart + zero deg (fence-free fusion)
    cvt_fused_kernel<<<CVB + 2 * NSCB, 256, 0, stream>>>(x, xnfH, batch, gstart, deg);
    // 2-5: CSR
    hist_kernel<<<(NE + 255) / 256, 256, 0, stream>>>(dst, deg);
    scan_bsum_kernel<<<NSCB, 256, 0, stream>>>(deg, bsum);
    scan_boff_kernel<<<1, 256, 0, stream>>>(bsum, boff, offv);
    scan_final_kernel<<<NSCB, 256, 0, stream>>>(deg, boff, offv, cursor);
    build_kernel<<<(NE + 255) / 256, 256, 0, stream>>>(src, dst, cursor, elist);

    // GIN layer 1
    gather_kernel<0><<<GAB, 256, 0, stream>>>(xnfH, offv, elist, aggH, nullptr);
    gin2_kernel<<<SROWS, 256, GIN_LDS, stream>>>(aggH, W0a, W0b, tAH, sscr, NND);
    stats_reduce_kernel<128><<<16, 256, 0, stream>>>(sscr, SROWS, g0, b0, cs + 0, 1);

    // GIN layer 2 (gather applies affine0+relu)
    gather_kernel<1><<<GAB, 256, 0, stream>>>(tAH, offv, elist, aggH, cs + 0);
    gin2_kernel<<<SROWS, 256, GIN_LDS, stream>>>(aggH, W1a, W1b, tAH, sscr, NND);
    stats_reduce_kernel<128><<<16, 256, 0, stream>>>(sscr, SROWS, g1, b1, cs + 256, 1);

    // bottleneck MLP
    mgemm_kernel<128,64,0,1,1,0><<<g1x, 256, 0, stream>>>(tAH, Wm0, bm0, nullptr, t5H, sscr, cs + 256, cs + 384, NND);
    stats_reduce_kernel<64><<<8, 256, 0, stream>>>(sscr, SROWS, gm, bm, cs + 512, 1);
    mgemm_kernel<64,128,0,1,2,2><<<g2, 256, 0, stream>>>(t5H, Wm1, bm1, nodef, ndH, sscr, cs + 512, cs + 576, NND);
    stats_reduce_kernel<128><<<16, 256, 0, stream>>>(sscr, SROWS, nullptr, nullptr, cs + 640, 0);
    mgemm_kernel<128,128,2,0,0,0><<<g2, 256, 0, stream>>>(ndH, Wfc1, bfc1, nullptr, tBH, nullptr, nullptr, nullptr, NND);

    // assign + noisy + kl partials (fence-free fusion)
    noisy_kernel<<<NOISY_BLOCKS, 256, 0, stream>>>(nodef, tBH, Wfc2, bfc2, cs + 640,
                                                   abuf, assn, kpart, kg0, kg1, kn0, kn1);

    // graph pooling + merged reduce+head
    graph_emb_part_kernel<<<NG * EMB_SPLIT, 128, 0, stream>>>(abuf, gstart, gpart);
    emb_head_kernel<<<NG, 128, 0, stream>>>(gpart, gstart, protos, Wlast,
                                            out, out + 256, out + 512, out + 16898, out + 18178);

    // penalties
    adj_kernel<<<ADJ_BLOCKS, 256, 0, stream>>>(assn, src, dst, adjp);
    final_scalar_kernel<<<1, 256, 0, stream>>>(kpart, adjp, out);
}

// Round 15
// 300.642 us; speedup vs baseline: 2.3557x; 1.0129x over previous
//
#include <hip/hip_runtime.h>
#include <hip/hip_bf16.h>
#include <stdint.h>

#define NND 40000
#define NE  640000
#define NG  128
#define DIM 128
#define HID 64
#define ADJ_BLOCKS 640
#define NOISY_BLOCKS 5000   // NND*32/256
#define NSCB ((NND + 255) / 256)   // 157 scan blocks
#define EMB_SPLIT 8
#define SROWS 313            // gemm row blocks (128 rows each) = stats rows
#define CVB 2500             // convert blocks

typedef short v8s __attribute__((ext_vector_type(8)));
typedef float v4f __attribute__((ext_vector_type(4)));

// ---------------- threefry2x32 (20 rounds), JAX-compatible ----------------
__host__ __device__ inline uint32_t rotl32(uint32_t v, uint32_t r) {
    return (v << r) | (v >> (32u - r));
}

__host__ __device__ inline void threefry2x32(uint32_t k0, uint32_t k1,
                                             uint32_t& x0, uint32_t& x1) {
    uint32_t k2 = k0 ^ k1 ^ 0x1BD11BDAu;
    x0 += k0; x1 += k1;
#define TFR(r) { x0 += x1; x1 = rotl32(x1, r); x1 ^= x0; }
    TFR(13u) TFR(15u) TFR(26u) TFR(6u)
    x0 += k1; x1 += k2 + 1u;
    TFR(17u) TFR(29u) TFR(16u) TFR(24u)
    x0 += k2; x1 += k0 + 2u;
    TFR(13u) TFR(15u) TFR(26u) TFR(6u)
    x0 += k0; x1 += k1 + 3u;
    TFR(17u) TFR(29u) TFR(16u) TFR(24u)
    x0 += k1; x1 += k2 + 4u;
    TFR(13u) TFR(15u) TFR(26u) TFR(6u)
    x0 += k2; x1 += k0 + 5u;
#undef TFR
}

__device__ inline float rbits_u01(uint32_t k0, uint32_t k1, uint32_t idx) {
    uint32_t x0 = 0u, x1 = idx;
    threefry2x32(k0, k1, x0, x1);
    uint32_t b = x0 ^ x1;
    return __uint_as_float((b >> 9) | 0x3f800000u) - 1.0f;
}

__device__ inline ushort bfbits(float a) {
    __hip_bfloat16 h = __float2bfloat16(a);
    return *(ushort*)&h;
}

__device__ inline uint32_t bfpack(float a, float b) {
    return (uint32_t)bfbits(a) | ((uint32_t)bfbits(b) << 16);
}

#define UNPACK8(v, f)                                                     \
    f[0] = __uint_as_float((v).x << 16); f[1] = __uint_as_float((v).x & 0xffff0000u); \
    f[2] = __uint_as_float((v).y << 16); f[3] = __uint_as_float((v).y & 0xffff0000u); \
    f[4] = __uint_as_float((v).z << 16); f[5] = __uint_as_float((v).z & 0xffff0000u); \
    f[6] = __uint_as_float((v).w << 16); f[7] = __uint_as_float((v).w & 0xffff0000u);

// ---------------- fused convert: x->bf16, gstart, zero deg ----------
__global__ __launch_bounds__(256) void cvt_fused_kernel(const float* __restrict__ in,
                                                        ushort* __restrict__ outh,
                                                        const int* __restrict__ batch,
                                                        int* __restrict__ gstart,
                                                        int* __restrict__ deg) {
    int blk = blockIdx.x, t = threadIdx.x;
    if (blk < CVB) {
        int i = blk * 256 + t;
        const float4* p = (const float4*)in + (size_t)i * 2;
        float4 a = p[0], b = p[1];
        uint4 o;
        o.x = bfpack(a.x, a.y); o.y = bfpack(a.z, a.w);
        o.z = bfpack(b.x, b.y); o.w = bfpack(b.z, b.w);
        *(uint4*)(outh + (size_t)i * 8) = o;
    } else if (blk < CVB + NSCB) {
        int i = (blk - CVB) * 256 + t;
        if (i < NND) {
            int b = batch[i];
            int prev = (i == 0) ? -1 : batch[i - 1];
            for (int g = prev + 1; g <= b; g++) gstart[g] = i;
            if (i == NND - 1)
                for (int g = b + 1; g <= NG; g++) gstart[g] = NND;
        }
    } else {
        int i = (blk - CVB - NSCB) * 256 + t;
        if (i < NND) deg[i] = 0;
    }
}

// ---------------- CSR build ----------------
__global__ __launch_bounds__(256) void hist_kernel(const int* __restrict__ dst,
                                                   int* __restrict__ deg) {
    int e = blockIdx.x * 256 + threadIdx.x;
    if (e < NE) atomicAdd(&deg[dst[e]], 1);
}

__global__ __launch_bounds__(256) void scan_bsum_kernel(const int* __restrict__ deg,
                                                        int* __restrict__ bsum) {
    int t = threadIdx.x;
    int i = blockIdx.x * 256 + t;
    int v = (i < NND) ? deg[i] : 0;
    __shared__ int sh[256];
    sh[t] = v;
    __syncthreads();
#pragma unroll
    for (int s = 128; s > 0; s >>= 1) {
        if (t < s) sh[t] += sh[t + s];
        __syncthreads();
    }
    if (t == 0) bsum[blockIdx.x] = sh[0];
}

// scan_final absorbs boff: each block redundantly scans the 157 block sums.
__global__ __launch_bounds__(256) void scan_final_kernel(const int* __restrict__ deg,
                                                         const int* __restrict__ bsum,
                                                         int* __restrict__ offv,
                                                         int* __restrict__ cursor) {
    int t = threadIdx.x;
    __shared__ int sb[256];
    int bv = (t < NSCB) ? bsum[t] : 0;
    sb[t] = bv;
    __syncthreads();
    for (int d = 1; d < 256; d <<= 1) {
        int u = (t >= d) ? sb[t - d] : 0;
        __syncthreads();
        sb[t] += u;
        __syncthreads();
    }
    int boff = (blockIdx.x == 0) ? 0 : sb[blockIdx.x - 1];
    if (blockIdx.x == 0 && t == 0) offv[NND] = sb[NSCB - 1];

    __shared__ int sh[256];
    int i = blockIdx.x * 256 + t;
    int v = (i < NND) ? deg[i] : 0;
    sh[t] = v;
    __syncthreads();
    for (int d = 1; d < 256; d <<= 1) {
        int u = (t >= d) ? sh[t - d] : 0;
        __syncthreads();
        sh[t] += u;
        __syncthreads();
    }
    int off = boff + sh[t] - v;
    if (i < NND) { offv[i] = off; cursor[i] = off; }
}

__global__ __launch_bounds__(256) void build_kernel(const int* __restrict__ src,
                                                    const int* __restrict__ dst,
                                                    int* __restrict__ cursor,
                                                    int* __restrict__ elist) {
    int e = blockIdx.x * 256 + threadIdx.x;
    if (e < NE) {
        int p = atomicAdd(&cursor[dst[e]], 1);
        elist[p] = src[e];
    }
}

// ---------------- gather: wave/node, 4 edge-slots x 16 col-slots; bf16 in/out.
template <int AFF>
__global__ __launch_bounds__(256) void gather_kernel(const ushort* __restrict__ feath,
                                                     const int* __restrict__ offv,
                                                     const int* __restrict__ elist,
                                                     ushort* __restrict__ aggh,
                                                     const float* __restrict__ cs) {
    int gt = blockIdx.x * 256 + threadIdx.x;
    int n = gt >> 6;
    int lane = threadIdx.x & 63;
    int e = lane >> 4, c = lane & 15;
    const uint4* F = (const uint4*)feath;
    int o0 = offv[n], o1 = offv[n + 1];

    float sc[8], sh[8];
    if (AFF) {
#pragma unroll
        for (int j = 0; j < 8; j++) {
            sc[j] = cs[c * 8 + j];
            sh[j] = cs[DIM + c * 8 + j];
        }
    }

    float acc[8];
    if (e == 0) {
        uint4 v = F[(size_t)n * 16 + c];
        UNPACK8(v, acc)
        if (AFF) {
#pragma unroll
            for (int j = 0; j < 8; j++) acc[j] = fmaxf(fmaf(acc[j], sc[j], sh[j]), 0.f);
        }
    } else {
#pragma unroll
        for (int j = 0; j < 8; j++) acc[j] = 0.f;
    }

    for (int i = o0 + e; i < o1; i += 4) {
        int s = elist[i];
        uint4 v = F[(size_t)s * 16 + c];
        float f[8];
        UNPACK8(v, f)
        if (AFF) {
#pragma unroll
            for (int j = 0; j < 8; j++) f[j] = fmaxf(fmaf(f[j], sc[j], sh[j]), 0.f);
        }
#pragma unroll
        for (int j = 0; j < 8; j++) acc[j] += f[j];
    }

#pragma unroll
    for (int j = 0; j < 8; j++) {
        acc[j] += __shfl_xor(acc[j], 16);
        acc[j] += __shfl_xor(acc[j], 32);
    }

    uint32_t wv;
    if (e == 0)      wv = bfpack(acc[0], acc[1]);
    else if (e == 1) wv = bfpack(acc[2], acc[3]);
    else if (e == 2) wv = bfpack(acc[4], acc[5]);
    else             wv = bfpack(acc[6], acc[7]);
    ((uint32_t*)aggh)[(size_t)n * 64 + c * 4 + e] = wv;
}

// ---------------- fused GIN double-GEMM (stats partials only) ---------
__global__ __launch_bounds__(256) void gin2_kernel(const ushort* __restrict__ Ah,
                                                   const float* __restrict__ Wa,
                                                   const float* __restrict__ Wb,
                                                   ushort* __restrict__ outh,
                                                   float* __restrict__ sscr,
                                                   int nrows) {
    constexpr int K = 128, KP = 136;
    extern __shared__ ushort lds[];
    ushort* B1 = lds;                 // KP*128
    ushort* B2 = lds + 128 * KP;      // KP*128

    const int t = threadIdx.x;
    const int w = t >> 6, l = t & 63;
    const int lm = l & 15, lk = l >> 4;
    const int row0 = blockIdx.x * 128 + w * 32;

    uint4 areg[2][4];
#pragma unroll
    for (int rf = 0; rf < 2; rf++) {
        int r = row0 + rf * 16 + lm;
        const ushort* ap = Ah + (size_t)min(r, nrows - 1) * K + lk * 8;
#pragma unroll
        for (int kc = 0; kc < 4; kc++)
            areg[rf][kc] = *(const uint4*)(ap + kc * 32);
    }

    for (int idx = t; idx < K * K; idx += 256) {
        int k = idx >> 7, c = idx & 127;
        B1[c * KP + k] = bfbits(Wa[idx]);
        B2[c * KP + k] = bfbits(Wb[idx]);
    }
    __syncthreads();

    v4f acc[2][8];
#pragma unroll
    for (int i = 0; i < 2; i++)
#pragma unroll
        for (int j = 0; j < 8; j++) acc[i][j] = (v4f){0.f, 0.f, 0.f, 0.f};

#pragma unroll
    for (int kc = 0; kc < 4; kc++) {
        v8s a0 = *(const v8s*)&areg[0][kc];
        v8s a1 = *(const v8s*)&areg[1][kc];
#pragma unroll
        for (int nc = 0; nc < 8; nc++) {
            v8s bfr = *(const v8s*)(B1 + (nc * 16 + lm) * KP + kc * 32 + lk * 8);
            acc[0][nc] = __builtin_amdgcn_mfma_f32_16x16x32_bf16(a0, bfr, acc[0][nc], 0, 0, 0);
            acc[1][nc] = __builtin_amdgcn_mfma_f32_16x16x32_bf16(a1, bfr, acc[1][nc], 0, 0, 0);
        }
    }

    __syncthreads();
#pragma unroll
    for (int rf = 0; rf < 2; rf++)
#pragma unroll
        for (int nc = 0; nc < 8; nc++)
#pragma unroll
            for (int reg = 0; reg < 4; reg++) {
                int r = w * 32 + rf * 16 + lk * 4 + reg;
                int c = nc * 16 + lm;
                B1[r * KP + c] = bfbits(fmaxf(acc[rf][nc][reg], 0.f));
            }
    __syncthreads();

    v4f acc2[2][8];
#pragma unroll
    for (int i = 0; i < 2; i++)
#pragma unroll
        for (int j = 0; j < 8; j++) acc2[i][j] = (v4f){0.f, 0.f, 0.f, 0.f};

#pragma unroll
    for (int kc = 0; kc < 4; kc++) {
        v8s a0 = *(const v8s*)(B1 + (w * 32 + lm) * KP + kc * 32 + lk * 8);
        v8s a1 = *(const v8s*)(B1 + (w * 32 + 16 + lm) * KP + kc * 32 + lk * 8);
#pragma unroll
        for (int nc = 0; nc < 8; nc++) {
            v8s bfr = *(const v8s*)(B2 + (nc * 16 + lm) * KP + kc * 32 + lk * 8);
            acc2[0][nc] = __builtin_amdgcn_mfma_f32_16x16x32_bf16(a0, bfr, acc2[0][nc], 0, 0, 0);
            acc2[1][nc] = __builtin_amdgcn_mfma_f32_16x16x32_bf16(a1, bfr, acc2[1][nc], 0, 0, 0);
        }
    }

    float ps[8], pq[8];
#pragma unroll
    for (int nc = 0; nc < 8; nc++) { ps[nc] = 0.f; pq[nc] = 0.f; }

#pragma unroll
    for (int nc = 0; nc < 8; nc++) {
        int cg = nc * 16 + lm;
#pragma unroll
        for (int rf = 0; rf < 2; rf++)
#pragma unroll
            for (int reg = 0; reg < 4; reg++) {
                int rg = row0 + rf * 16 + lk * 4 + reg;
                if (rg < nrows) {
                    float v = fmaxf(acc2[rf][nc][reg], 0.f);
                    outh[(size_t)rg * K + cg] = bfbits(v);
                    ps[nc] += v; pq[nc] += v * v;
                }
            }
    }

    __syncthreads();
    float* scr = (float*)lds;
#pragma unroll
    for (int nc = 0; nc < 8; nc++) {
        ps[nc] += __shfl_xor(ps[nc], 16); ps[nc] += __shfl_xor(ps[nc], 32);
        pq[nc] += __shfl_xor(pq[nc], 16); pq[nc] += __shfl_xor(pq[nc], 32);
    }
    if (lk == 0) {
#pragma unroll
        for (int nc = 0; nc < 8; nc++) {
            scr[w * 128 + nc * 16 + lm]       = ps[nc];
            scr[512 + w * 128 + nc * 16 + lm] = pq[nc];
        }
    }
    __syncthreads();
    if (t < 128) {
        float s = scr[t] + scr[128 + t] + scr[256 + t] + scr[384 + t];
        float q = scr[512 + t] + scr[640 + t] + scr[768 + t] + scr[896 + t];
        sscr[(size_t)blockIdx.x * 256 + t]       = s;
        sscr[(size_t)blockIdx.x * 256 + 128 + t] = q;
    }
}

// ---------------- MFMA GEMM (single), stats partials only ----------------
template <int K, int M, int ACT, int STATS, int PRE, int OUTM>
__global__ __launch_bounds__(256) void mgemm_kernel(const ushort* __restrict__ Ah,
                                                    const float* __restrict__ W,
                                                    const float* __restrict__ bias,
                                                    float* __restrict__ outf,
                                                    ushort* __restrict__ outh,
                                                    float* __restrict__ sscr,
                                                    const float* __restrict__ pscale,
                                                    const float* __restrict__ pshift,
                                                    int nrows) {
    constexpr int KP  = K + 8;
    constexpr int NKC = K / 32;
    __shared__ __align__(16) ushort sW[64 * KP];

    const int t = threadIdx.x;
    const int w = t >> 6, l = t & 63;
    const int lm = l & 15, lk = l >> 4;
    const int col0 = blockIdx.y * 64;
    const int row0 = blockIdx.x * 128 + w * 32;

    for (int idx = t; idx < K * 64; idx += 256) {
        int k = idx >> 6, c = idx & 63;
        sW[c * KP + k] = bfbits(W[(size_t)k * M + col0 + c]);
    }

    uint4 areg[2][NKC];
#pragma unroll
    for (int rf = 0; rf < 2; rf++) {
        int r = row0 + rf * 16 + lm;
        const ushort* ap = Ah + (size_t)min(r, nrows - 1) * K + lk * 8;
#pragma unroll
        for (int kc = 0; kc < NKC; kc++)
            areg[rf][kc] = *(const uint4*)(ap + kc * 32);
    }

    __syncthreads();

    v4f acc[2][4];
#pragma unroll
    for (int i = 0; i < 2; i++)
#pragma unroll
        for (int j = 0; j < 4; j++) acc[i][j] = (v4f){0.f, 0.f, 0.f, 0.f};

#pragma unroll
    for (int kc = 0; kc < NKC; kc++) {
        v8s bfr[4];
#pragma unroll
        for (int nc = 0; nc < 4; nc++)
            bfr[nc] = *(const v8s*)(sW + (nc * 16 + lm) * KP + kc * 32 + lk * 8);

        v8s afr[2];
#pragma unroll
        for (int rf = 0; rf < 2; rf++) {
            if (PRE > 0) {
                int k0 = kc * 32 + lk * 8;
                float f[8];
                uint4 v = areg[rf][kc];
                UNPACK8(v, f)
                float4 s0 = *(const float4*)(pscale + k0);
                float4 s1 = *(const float4*)(pscale + k0 + 4);
                float4 h0 = *(const float4*)(pshift + k0);
                float4 h1 = *(const float4*)(pshift + k0 + 4);
                f[0] = fmaf(f[0], s0.x, h0.x); f[1] = fmaf(f[1], s0.y, h0.y);
                f[2] = fmaf(f[2], s0.z, h0.z); f[3] = fmaf(f[3], s0.w, h0.w);
                f[4] = fmaf(f[4], s1.x, h1.x); f[5] = fmaf(f[5], s1.y, h1.y);
                f[6] = fmaf(f[6], s1.z, h1.z); f[7] = fmaf(f[7], s1.w, h1.w);
                if (PRE == 2) {
#pragma unroll
                    for (int e2 = 0; e2 < 8; e2++) f[e2] = fmaxf(f[e2], 0.f);
                }
                v8s a;
#pragma unroll
                for (int e2 = 0; e2 < 8; e2++) a[e2] = (short)bfbits(f[e2]);
                afr[rf] = a;
            } else {
                afr[rf] = *(const v8s*)&areg[rf][kc];
            }
        }

#pragma unroll
        for (int rf = 0; rf < 2; rf++)
#pragma unroll
            for (int nc = 0; nc < 4; nc++)
                acc[rf][nc] = __builtin_amdgcn_mfma_f32_16x16x32_bf16(
                    afr[rf], bfr[nc], acc[rf][nc], 0, 0, 0);
    }

    float ps[4], pq[4];
#pragma unroll
    for (int nc = 0; nc < 4; nc++) { ps[nc] = 0.f; pq[nc] = 0.f; }

#pragma unroll
    for (int nc = 0; nc < 4; nc++) {
        int cg = col0 + nc * 16 + lm;
        float bv = bias ? bias[cg] : 0.f;
#pragma unroll
        for (int rf = 0; rf < 2; rf++) {
#pragma unroll
            for (int reg = 0; reg < 4; reg++) {
                int rg = row0 + rf * 16 + lk * 4 + reg;
                if (rg < nrows) {
                    float v = acc[rf][nc][reg] + bv;
                    if (ACT == 1) v = fmaxf(v, 0.f);
                    if (ACT == 2) v = tanhf(v);
                    if (OUTM != 0) outf[(size_t)rg * M + cg] = v;
                    if (OUTM != 1) outh[(size_t)rg * M + cg] = bfbits(v);
                    ps[nc] += v; pq[nc] += v * v;
                }
            }
        }
    }

    if (STATS) {
        __syncthreads();
        float* scr = (float*)sW;
#pragma unroll
        for (int nc = 0; nc < 4; nc++) {
            ps[nc] += __shfl_xor(ps[nc], 16); ps[nc] += __shfl_xor(ps[nc], 32);
            pq[nc] += __shfl_xor(pq[nc], 16); pq[nc] += __shfl_xor(pq[nc], 32);
        }
        if (lk == 0) {
#pragma unroll
            for (int nc = 0; nc < 4; nc++) {
                scr[w * 64 + nc * 16 + lm]       = ps[nc];
                scr[256 + w * 64 + nc * 16 + lm] = pq[nc];
            }
        }
        __syncthreads();
        if (t < 64) {
            float s = scr[t] + scr[64 + t] + scr[128 + t] + scr[192 + t];
            float q = scr[256 + t] + scr[320 + t] + scr[384 + t] + scr[448 + t];
            sscr[(size_t)blockIdx.x * 2 * M + col0 + t]     = s;
            sscr[(size_t)blockIdx.x * 2 * M + M + col0 + t] = q;
        }
    }
}

// reduce stats partials; affine=1: write (scale, shift); else raw (sum,sumsq).
template <int M>
__global__ __launch_bounds__(256) void stats_reduce_kernel(const float* __restrict__ sscr,
                                                           int nblk,
                                                           const float* __restrict__ g,
                                                           const float* __restrict__ b,
                                                           float* __restrict__ cs,
                                                           int affine) {
    const int cols = 2 * M;
    const int t = threadIdx.x;
    const int c = blockIdx.x * 8 + (t & 7);
    const int rl = t >> 3;
    float s = 0.f, q = 0.f;
    for (int r = rl; r < nblk; r += 32) {
        s += sscr[(size_t)r * cols + c];
        q += sscr[(size_t)r * cols + M + c];
    }
    __shared__ float shs[256], shq[256];
    shs[t] = s; shq[t] = q;
    __syncthreads();
#pragma unroll
    for (int st = 128; st >= 8; st >>= 1) {
        if (t < st) { shs[t] += shs[t + st]; shq[t] += shq[t + st]; }
        __syncthreads();
    }
    if (t < 8) {
        float ss = shs[t], qq = shq[t];
        if (affine) {
            const float invN = 1.0f / (float)NND;
            float mu = ss * invN;
            float var = fmaxf(qq * invN - mu * mu, 0.f);
            float sc = g[c] * rsqrtf(var + 1e-5f);
            cs[c] = sc;
            cs[M + c] = b[c] - mu * sc;
        } else {
            cs[c] = ss;
            cs[M + c] = qq;
        }
    }
}

// ---------------- fused assign + noisy + kl partials (bf16 node_feature) --------
__global__ __launch_bounds__(256) void noisy_kernel(const ushort* __restrict__ ndH,
                                                    const ushort* __restrict__ a1h,
                                                    const float* __restrict__ Wfc2,
                                                    const float* __restrict__ bfc2,
                                                    const float* __restrict__ cs3,
                                                    ushort* __restrict__ noisyh,
                                                    float* __restrict__ assn,
                                                    float* __restrict__ kpart,
                                                    uint32_t kg0, uint32_t kg1,
                                                    uint32_t kn0, uint32_t kn1) {
    __shared__ float wsh[DIM * 2];
    int t = threadIdx.x;
    wsh[t] = Wfc2[t];
    __syncthreads();

    int gt = blockIdx.x * 256 + t;
    int n = gt >> 5, c4 = t & 31, d = c4 * 4;

    float d0 = 0.f, d1 = 0.f;
    {
        uint2 av = *(const uint2*)(a1h + (size_t)n * DIM + d);
        float a0 = __uint_as_float(av.x << 16);
        float a1 = __uint_as_float(av.x & 0xffff0000u);
        float a2 = __uint_as_float(av.y << 16);
        float a3 = __uint_as_float(av.y & 0xffff0000u);
        d0 = a0 * wsh[2 * d] + a1 * wsh[2 * (d + 1)] + a2 * wsh[2 * (d + 2)] + a3 * wsh[2 * (d + 3)];
        d1 = a0 * wsh[2 * d + 1] + a1 * wsh[2 * (d + 1) + 1] + a2 * wsh[2 * (d + 2) + 1] + a3 * wsh[2 * (d + 3) + 1];
    }
#pragma unroll
    for (int s = 16; s > 0; s >>= 1) {
        d0 += __shfl_xor(d0, s);
        d1 += __shfl_xor(d1, s);
    }

    float la0 = 0.f, la1 = 0.f;
    if (c4 == 0) {
        float dd0 = d0 + bfc2[0], dd1 = d1 + bfc2[1];
        float m = fmaxf(dd0, dd1);
        float e0 = expf(dd0 - m), e1 = expf(dd1 - m);
        float inv = 1.f / (e0 + e1);
        float as0 = e0 * inv, as1 = e1 * inv;
        assn[2 * n] = as0; assn[2 * n + 1] = as1;

        float uf0 = rbits_u01(kg0, kg1, (uint32_t)(2 * n));
        float uf1 = rbits_u01(kg0, kg1, (uint32_t)(2 * n + 1));
        float u0 = fmaxf(1e-10f, uf0 + 1e-10f);
        float u1 = fmaxf(1e-10f, uf1 + 1e-10f);
        float gu0 = -logf(-logf(u0));
        float gu1 = -logf(-logf(u1));
        float y0 = as0 + gu0, y1 = as1 + gu1;
        float mm = fmaxf(y0, y1);
        float f0 = expf(y0 - mm), f1 = expf(y1 - mm);
        float iv = 1.f / (f0 + f1);
        la0 = f0 * iv; la1 = f1 * iv;
    }
    la0 = __shfl(la0, 0, 32);
    la1 = __shfl(la1, 0, 32);

    const float invN = 1.0f / (float)NND;
    uint2 xv = *(const uint2*)(ndH + (size_t)n * DIM + d);
    float xa[4];
    xa[0] = __uint_as_float(xv.x << 16);
    xa[1] = __uint_as_float(xv.x & 0xffff0000u);
    xa[2] = __uint_as_float(xv.y << 16);
    xa[3] = __uint_as_float(xv.y & 0xffff0000u);
    float t1 = 0.f, t2 = 0.f, o[4];
#pragma unroll
    for (int j = 0; j < 4; j++) {
        float mu = cs3[d + j] * invN;
        float q = cs3[DIM + d + j];
        float var1 = fmaxf(q - (float)NND * mu * mu, 0.f) / (float)(NND - 1);
        float sd = sqrtf(var1);
        float r = rbits_u01(kn0, kn1, (uint32_t)(n * DIM + d + j));
        float nm = la0 * xa[j] + la1 * mu;
        float ns = la1 * sd;
        o[j] = fmaf(r, ns, nm);
        float inv = 1.0f / (sd + 1e-7f);
        float z1 = ns * inv;            t1 += z1 * z1;
        float z2 = (nm - mu) * inv;     t2 += z2 * z2;
    }
    uint2 ov;
    ov.x = bfpack(o[0], o[1]);
    ov.y = bfpack(o[2], o[3]);
    *(uint2*)(noisyh + (size_t)n * DIM + d) = ov;

    __shared__ float s1[256], s2[256];
    s1[t] = t1; s2[t] = t2;
    __syncthreads();
    for (int s = 128; s > 0; s >>= 1) {
        if (t < s) { s1[t] += s1[t + s]; s2[t] += s2[t + s]; }
        __syncthreads();
    }
    if (t == 0) { kpart[2 * blockIdx.x] = s1[0]; kpart[2 * blockIdx.x + 1] = s2[0]; }
}

// ---------------- graph pooling partials (bf16 noisy) ----------------
__global__ __launch_bounds__(128) void graph_emb_part_kernel(const ushort* __restrict__ noisyh,
                                                             const int* __restrict__ gstart,
                                                             float* __restrict__ gpart) {
    int g = blockIdx.x / EMB_SPLIT;
    int sidx = blockIdx.x % EMB_SPLIT;
    int c = threadIdx.x;
    int s = gstart[g], e = gstart[g + 1];
    int len = e - s;
    int chunk = (len + EMB_SPLIT - 1) / EMB_SPLIT;
    int r0 = s + sidx * chunk;
    int r1 = min(r0 + chunk, e);
    float acc = 0.f;
    for (int r = r0; r < r1; r++) {
        ushort b = noisyh[(size_t)r * DIM + c];
        acc += __uint_as_float((uint32_t)b << 16);
    }
    gpart[((size_t)g * EMB_SPLIT + sidx) * DIM + c] = acc;
}

// ---------------- merged emb reduce + head + final scalars (block NG) ----------
__global__ __launch_bounds__(128) void emb_head_kernel(const float* __restrict__ gpart,
                                                       const int* __restrict__ gstart,
                                                       const float* __restrict__ protos,
                                                       const float* __restrict__ Wlast,
                                                       const float* __restrict__ kpart,
                                                       const float* __restrict__ adjp,
                                                       float* __restrict__ out_logits,
                                                       float* __restrict__ out_probs,
                                                       float* __restrict__ emb_out,
                                                       float* __restrict__ out_sim,
                                                       float* __restrict__ out_dist,
                                                       float* __restrict__ out_scalars) {
    int g = blockIdx.x, c = threadIdx.x;

    if (g == NG) {
        // final scalars: reduce kl + adj partials (128 threads)
        float k1 = 0.f, k2 = 0.f, a0 = 0.f, a1 = 0.f, a2 = 0.f, a3 = 0.f;
        for (int i = c; i < NOISY_BLOCKS; i += 128) {
            float2 v = ((const float2*)kpart)[i];
            k1 += v.x; k2 += v.y;
        }
        for (int i = c; i < ADJ_BLOCKS; i += 128) {
            float4 v = ((const float4*)adjp)[i];
            a0 += v.x; a1 += v.y; a2 += v.z; a3 += v.w;
        }
        __shared__ float sh[6 * 128];
        sh[c] = k1; sh[128 + c] = k2; sh[256 + c] = a0;
        sh[384 + c] = a1; sh[512 + c] = a2; sh[640 + c] = a3;
        __syncthreads();
        for (int s = 64; s > 0; s >>= 1) {
            if (c < s) {
#pragma unroll
                for (int v = 0; v < 6; v++) sh[v * 128 + c] += sh[v * 128 + c + s];
            }
            __syncthreads();
        }
        if (c == 0) {
            float kl = 0.5f / ((float)NND * (float)DIM) * sh[0] + (1.0f / (float)DIM) * sh[128];
            out_scalars[16896] = kl;
            float a00 = sh[256], a01 = sh[384], a10 = sh[512], a11 = sh[640];
            float r0 = fmaxf(fabsf(a00) + fabsf(a01), 1e-12f);
            float r1 = fmaxf(fabsf(a10) + fabsf(a11), 1e-12f);
            float d0 = a00 / r0 - 1.f, d1 = a11 / r1 - 1.f;
            out_scalars[16897] = 0.5f * (d0 * d0 + d1 * d1);
        }
        return;
    }

    float tot = 0.f;
#pragma unroll
    for (int si = 0; si < EMB_SPLIT; si++)
        tot += gpart[((size_t)g * EMB_SPLIT + si) * DIM + c];
    float cntf = (float)(gstart[g + 1] - gstart[g]);
    float ev = tot / fmaxf(cntf, 1.f);
    emb_out[(size_t)g * DIM + c] = ev;

    __shared__ float se[DIM];
    se[c] = ev;
    __syncthreads();

    if (c < 64) {
        int l = c;
        float ge0 = se[l], ge1 = se[l + 64];
        float gn = ge0 * ge0 + ge1 * ge1;
        float dj[10], pj[10];
#pragma unroll
        for (int j = 0; j < 10; j++) {
            float pa = protos[j * DIM + l], pb = protos[j * DIM + l + 64];
            dj[j] = ge0 * pa + ge1 * pb;
            pj[j] = pa * pa + pb * pb;
        }
        float wl0 = ge0 * Wlast[10 + l] + ge1 * Wlast[10 + l + 64];
        float wl1 = ge0 * Wlast[138 + 10 + l] + ge1 * Wlast[138 + 10 + l + 64];
#pragma unroll
        for (int sft = 32; sft > 0; sft >>= 1) {
            gn += __shfl_xor(gn, sft);
            wl0 += __shfl_xor(wl0, sft);
            wl1 += __shfl_xor(wl1, sft);
#pragma unroll
            for (int j = 0; j < 10; j++) {
                dj[j] += __shfl_xor(dj[j], sft);
                pj[j] += __shfl_xor(pj[j], sft);
            }
        }
        if (l == 0) {
            float lg0 = wl0, lg1 = wl1;
#pragma unroll
            for (int j = 0; j < 10; j++) {
                float dist = -2.f * dj[j] + gn + pj[j];
                float sv = logf((dist + 1.0f) / (dist + 1e-4f));
                out_dist[g * 10 + j] = dist;
                out_sim[g * 10 + j] = sv;
                lg0 = fmaf(Wlast[j], sv, lg0);
                lg1 = fmaf(Wlast[138 + j], sv, lg1);
            }
            out_logits[2 * g] = lg0; out_logits[2 * g + 1] = lg1;
            float m = fmaxf(lg0, lg1);
            float e0 = expf(lg0 - m), e1 = expf(lg1 - m);
            float iv = 1.f / (e0 + e1);
            out_probs[2 * g] = e0 * iv; out_probs[2 * g + 1] = e1 * iv;
        }
    }
}

// ---------------- adjacency partials ----------------
__global__ __launch_bounds__(256) void adj_kernel(const float* __restrict__ assn,
                                                  const int* __restrict__ src,
                                                  const int* __restrict__ dst,
                                                  float* __restrict__ adjp) {
    int t = threadIdx.x;
    float p00 = 0.f, p01 = 0.f, p10 = 0.f, p11 = 0.f;
    for (int e = blockIdx.x * 256 + t; e < NE; e += ADJ_BLOCKS * 256) {
        float2 a = *(const float2*)(assn + 2 * (size_t)src[e]);
        float2 b = *(const float2*)(assn + 2 * (size_t)dst[e]);
        p00 += a.x * b.x; p01 += a.x * b.y; p10 += a.y * b.x; p11 += a.y * b.y;
    }
    __shared__ float s0[256], s1[256], s2[256], s3[256];
    s0[t] = p00; s1[t] = p01; s2[t] = p10; s3[t] = p11;
    __syncthreads();
    for (int s = 128; s > 0; s >>= 1) {
        if (t < s) { s0[t] += s0[t + s]; s1[t] += s1[t + s]; s2[t] += s2[t + s]; s3[t] += s3[t + s]; }
        __syncthreads();
    }
    if (t == 0) {
        float4* o = (float4*)(adjp + 4 * (size_t)blockIdx.x);
        *o = make_float4(s0[0], s1[0], s2[0], s3[0]);
    }
}

// ---------------- launcher ----------------
extern "C" void kernel_launch(void* const* d_in, const int* in_sizes, int n_in,
                              void* d_out, int out_size, void* d_ws, size_t ws_size,
                              hipStream_t stream) {
    (void)in_sizes; (void)n_in; (void)out_size; (void)ws_size;
    const float* x     = (const float*)d_in[0];
    const int*   ei    = (const int*)d_in[1];
    const int*   batch = (const int*)d_in[2];
    const float* W0a   = (const float*)d_in[3];
    const float* W0b   = (const float*)d_in[4];
    const float* g0    = (const float*)d_in[5];
    const float* b0    = (const float*)d_in[6];
    const float* W1a   = (const float*)d_in[7];
    const float* W1b   = (const float*)d_in[8];
    const float* g1    = (const float*)d_in[9];
    const float* b1    = (const float*)d_in[10];
    const float* Wm0   = (const float*)d_in[11];
    const float* bm0   = (const float*)d_in[12];
    const float* gm    = (const float*)d_in[13];
    const float* bm    = (const float*)d_in[14];
    const float* Wm1   = (const float*)d_in[15];
    const float* bm1   = (const float*)d_in[16];
    const float* Wfc1  = (const float*)d_in[17];
    const float* bfc1  = (const float*)d_in[18];
    const float* Wfc2  = (const float*)d_in[19];
    const float* bfc2  = (const float*)d_in[20];
    const float* protos= (const float*)d_in[21];
    const float* Wlast = (const float*)d_in[22];
    const int* src = ei;
    const int* dst = ei + NE;
    float* out = (float*)d_out;

    // f32 region
    float* assn  = (float*)d_ws;                    // N*2
    float* cs    = assn + (size_t)NND * 2;          // 1024
    float* kpart = cs + 1024;                       // NOISY_BLOCKS*2
    float* adjp  = kpart + NOISY_BLOCKS * 2;        // ADJ_BLOCKS*4
    float* sscr  = adjp + ADJ_BLOCKS * 4;           // SROWS*256
    float* gpart = sscr + (size_t)SROWS * 256;      // NG*EMB_SPLIT*DIM
    // bf16 region
    ushort* aggH = (ushort*)(gpart + NG * EMB_SPLIT * DIM);  // N*128
    ushort* xnfH = aggH + (size_t)NND * DIM;                 // N*128 (x bf16 / noisy bf16)
    ushort* tBH  = xnfH + (size_t)NND * DIM;                 // N*128 (a1)
    ushort* tAH  = tBH + (size_t)NND * DIM;                  // N*128
    ushort* ndH  = tAH + (size_t)NND * DIM;                  // N*128 (node_feature)
    ushort* t5H  = ndH + (size_t)NND * DIM;                  // N*64
    // int region
    int* deg    = (int*)(t5H + (size_t)NND * HID);
    int* offv   = deg + NND;
    int* cursor = offv + NND + 1;
    int* elist  = cursor + NND;
    int* gstart = elist + NE;
    int* bsum   = gstart + NG + 1;

    // threefry keys on host
    uint32_t kg0 = 0u, kg1 = 0u; threefry2x32(0u, 42u, kg0, kg1);  // ctr (0,0)
    uint32_t kn0 = 0u, kn1 = 1u; threefry2x32(0u, 42u, kn0, kn1);  // ctr (0,1)

    const int GAB = NND / 4;
    const size_t GIN_LDS = 2u * 128u * 136u * sizeof(ushort);   // 69632 B
    dim3 g2(SROWS, 2), g1x(SROWS, 1);

    // 1: convert x + gstart + zero deg
    cvt_fused_kernel<<<CVB + 2 * NSCB, 256, 0, stream>>>(x, xnfH, batch, gstart, deg);
    // 2-4: CSR
    hist_kernel<<<(NE + 255) / 256, 256, 0, stream>>>(dst, deg);
    scan_bsum_kernel<<<NSCB, 256, 0, stream>>>(deg, bsum);
    scan_final_kernel<<<NSCB, 256, 0, stream>>>(deg, bsum, offv, cursor);
    build_kernel<<<(NE + 255) / 256, 256, 0, stream>>>(src, dst, cursor, elist);

    // GIN layer 1
    gather_kernel<0><<<GAB, 256, 0, stream>>>(xnfH, offv, elist, aggH, nullptr);
    gin2_kernel<<<SROWS, 256, GIN_LDS, stream>>>(aggH, W0a, W0b, tAH, sscr, NND);
    stats_reduce_kernel<128><<<16, 256, 0, stream>>>(sscr, SROWS, g0, b0, cs + 0, 1);

    // GIN layer 2 (gather applies affine0+relu)
    gather_kernel<1><<<GAB, 256, 0, stream>>>(tAH, offv, elist, aggH, cs + 0);
    gin2_kernel<<<SROWS, 256, GIN_LDS, stream>>>(aggH, W1a, W1b, tAH, sscr, NND);
    stats_reduce_kernel<128><<<16, 256, 0, stream>>>(sscr, SROWS, g1, b1, cs + 256, 1);

    // bottleneck MLP
    mgemm_kernel<128,64,0,1,1,0><<<g1x, 256, 0, stream>>>(tAH, Wm0, bm0, nullptr, t5H, sscr, cs + 256, cs + 384, NND);
    stats_reduce_kernel<64><<<8, 256, 0, stream>>>(sscr, SROWS, gm, bm, cs + 512, 1);
    mgemm_kernel<64,128,0,1,2,0><<<g2, 256, 0, stream>>>(t5H, Wm1, bm1, nullptr, ndH, sscr, cs + 512, cs + 576, NND); // node_feature bf16 + f32 stats
    stats_reduce_kernel<128><<<16, 256, 0, stream>>>(sscr, SROWS, nullptr, nullptr, cs + 640, 0);
    mgemm_kernel<128,128,2,0,0,0><<<g2, 256, 0, stream>>>(ndH, Wfc1, bfc1, nullptr, tBH, nullptr, nullptr, nullptr, NND); // a1 bf16

    // assign + noisy + kl partials (bf16 in/out; noisy into xnfH, dead since layer1)
    noisy_kernel<<<NOISY_BLOCKS, 256, 0, stream>>>(ndH, tBH, Wfc2, bfc2, cs + 640,
                                                   xnfH, assn, kpart, kg0, kg1, kn0, kn1);

    // graph pooling partials, adjacency, then merged reduce+head+finals
    graph_emb_part_kernel<<<NG * EMB_SPLIT, 128, 0, stream>>>(xnfH, gstart, gpart);
    adj_kernel<<<ADJ_BLOCKS, 256, 0, stream>>>(assn, src, dst, adjp);
    emb_head_kernel<<<NG + 1, 128, 0, stream>>>(gpart, gstart, protos, Wlast, kpart, adjp,
                                                out, out + 256, out + 512, out + 16898, out + 18178, out);
}